// Round 1
// 724.315 us; speedup vs baseline: 1.0163x; 1.0163x over previous
//
#include <hip/hip_runtime.h>
#include <hip/hip_bf16.h>
#include <math.h>

typedef unsigned short ushort;
typedef __attribute__((ext_vector_type(8))) short short8;
typedef __attribute__((ext_vector_type(8))) unsigned short ushort8;
typedef __attribute__((ext_vector_type(4))) unsigned short ushort4v;
typedef __attribute__((ext_vector_type(4))) float f32x4;

__device__ __forceinline__ ushort f2bb(float v) {
    return __builtin_bit_cast(ushort, __float2bfloat16(v));
}
__device__ __forceinline__ float bf2f(ushort u) {
    return __bfloat162float(__builtin_bit_cast(__hip_bfloat16, u));
}
// async global->LDS 16B/lane; LDS dest = wave-uniform base + lane*16
__device__ __forceinline__ void gl2lds16(const ushort* g, ushort* l) {
    __builtin_amdgcn_global_load_lds(
        (const __attribute__((address_space(1))) unsigned int*)g,
        (__attribute__((address_space(3))) unsigned int*)l, 16, 0, 0);
}

// ---------------------------------------------------------------------------
// B=32, C=512, H=W=32, NH=8, dh=64, N=256 pooled, hidden=2048.
// GEMMs: m97-style — global_load_lds staging, unpadded 64B LDS rows, BK=32,
// 16x16x32 bf16 MFMA. All LN pre-applied so every GEMM A is plain row-major.
// Workspace (bytes), peak 84,410,368 (== round-3 proven size):
//   [0, 327680)               stats fp32
//   [524288, 8912896)         weights bf16: wq wp wcT w1 w2 (8 MiB)
//   A  [8912896,  +8MiB)      xp bf16 [32][512][256] -> t2 [8192][512]
//   Br [17301504, +8MiB)      a_ln [8192][512] -> y0 rows 0..8191
//   CD [25690112, +32MiB)     qkvp 24MiB + attn_o 8MiB -> h1c [8192][2048]
//   T  [59244544, +24MiB)     y0 rows 8192..32767
// ---------------------------------------------------------------------------

__global__ __launch_bounds__(256) void cvtw_k(const float* __restrict__ in,
                                              ushort* __restrict__ out, int n4) {
    int i = blockIdx.x * 256 + threadIdx.x;
    if (i >= n4) return;
    float4 v = ((const float4*)in)[i];
    ushort4v o;
    o.x = f2bb(v.x); o.y = f2bb(v.y); o.z = f2bb(v.z); o.w = f2bb(v.w);
    ((ushort4v*)out)[i] = o;
}

// ct_w [512][2048] fp32 -> [2048][512] bf16
__global__ __launch_bounds__(256) void cvtt_k(const float* __restrict__ in,
                                              ushort* __restrict__ out) {
    __shared__ float tl[32][33];
    int c0 = blockIdx.y * 32, j0 = blockIdx.x * 32;
    int tr = threadIdx.x >> 5, tc = threadIdx.x & 31;
#pragma unroll
    for (int p4 = 0; p4 < 4; ++p4)
        tl[tr + p4 * 8][tc] = in[(size_t)(c0 + tr + p4 * 8) * 2048 + j0 + tc];
    __syncthreads();
#pragma unroll
    for (int p4 = 0; p4 < 4; ++p4)
        out[(size_t)(j0 + tr + p4 * 8) * 512 + c0 + tc] = f2bb(tl[tc][tr + p4 * 8]);
}

// K1: depthwise 3x3 + bias + residual + 2x2 avgpool -> xp bf16 [B,C,16,16]
__global__ __launch_bounds__(256) void dwpool_k(const float* __restrict__ x,
                                                const float* __restrict__ dww,
                                                const float* __restrict__ dwb,
                                                ushort* __restrict__ xp) {
    int bc = blockIdx.x;
    int c = bc & 511;
    __shared__ float tile[32][33];
    __shared__ float w9[9];
    const float* xb = x + (size_t)bc * 1024;
    int tid = threadIdx.x;
    for (int i = tid; i < 1024; i += 256) tile[i >> 5][i & 31] = xb[i];
    if (tid < 9) w9[tid] = dww[c * 9 + tid];
    __syncthreads();
    float bv = dwb[c];
    int ph = tid >> 4, pw = tid & 15;
    float s = 0.f;
#pragma unroll
    for (int dy = 0; dy < 2; ++dy) {
#pragma unroll
        for (int dx = 0; dx < 2; ++dx) {
            int hh = 2 * ph + dy, ww = 2 * pw + dx;
            float a = bv + tile[hh][ww];
#pragma unroll
            for (int ky = 0; ky < 3; ++ky) {
                int yy = hh + ky - 1;
                if (yy < 0 || yy > 31) continue;
#pragma unroll
                for (int kx = 0; kx < 3; ++kx) {
                    int xx = ww + kx - 1;
                    if (xx < 0 || xx > 31) continue;
                    a += w9[ky * 3 + kx] * tile[yy][xx];
                }
            }
            s += a;
        }
    }
    xp[(size_t)bc * 256 + tid] = f2bb(0.25f * s);
}

// K2: LN1 stats per token over C=512; xp bf16 [b][c][n]
__global__ __launch_bounds__(256) void ln1_stats_k(const ushort* __restrict__ xp,
                                                   float* __restrict__ m1,
                                                   float* __restrict__ r1) {
    __shared__ float sh_s[4][64], sh_q[4][64];
    int blk = blockIdx.x;
    int b = blk >> 2;
    int n0 = (blk & 3) * 64;
    int t = threadIdx.x & 63, w = threadIdx.x >> 6;
    float s = 0.f, ss = 0.f;
    for (int i = 0; i < 128; ++i) {
        int c = w * 128 + i;
        float v = bf2f(xp[(size_t)(b * 512 + c) * 256 + n0 + t]);
        s += v; ss += v * v;
    }
    sh_s[w][t] = s; sh_q[w][t] = ss;
    __syncthreads();
    if (w == 0) {
        s  = sh_s[0][t] + sh_s[1][t] + sh_s[2][t] + sh_s[3][t];
        ss = sh_q[0][t] + sh_q[1][t] + sh_q[2][t] + sh_q[3][t];
        float m = s * (1.0f / 512.0f);
        m1[b * 256 + n0 + t] = m;
        r1[b * 256 + n0 + t] = rsqrtf(ss * (1.0f / 512.0f) - m * m + 1e-6f);
    }
}

// K3: LN1 apply + transpose: xp [b][c][n] -> a_ln [m][c] bf16 normalized
__global__ __launch_bounds__(256) void ln1_apply_k(const ushort* __restrict__ xp,
                                                   const float* __restrict__ m1,
                                                   const float* __restrict__ r1,
                                                   const float* __restrict__ g,
                                                   const float* __restrict__ beta,
                                                   ushort* __restrict__ a_ln) {
    __shared__ float tl[64][66];
    int blk = blockIdx.x;                 // b*32 + ct*4 + nt
    int b = blk >> 5, ct = (blk >> 2) & 7, nt = blk & 3;
    int t = threadIdx.x;
    int rq = t >> 6, nl = t & 63;
#pragma unroll
    for (int i = 0; i < 16; ++i) {
        int r = rq * 16 + i;
        int c = ct * 64 + r;
        tl[r][nl] = bf2f(xp[(size_t)(b * 512 + c) * 256 + nt * 64 + nl]);
    }
    __syncthreads();
    int r2 = t >> 2, cq = t & 3;
    int m = b * 256 + nt * 64 + r2;
    float mu = m1[m], rs = r1[m];
#pragma unroll
    for (int hh = 0; hh < 2; ++hh) {
        ushort8 o;
#pragma unroll
        for (int j = 0; j < 8; ++j) {
            int cl = cq * 16 + hh * 8 + j;
            int c = ct * 64 + cl;
            o[j] = f2bb((tl[cl][r2] - mu) * rs * g[c] + beta[c]);
        }
        *(ushort8*)&a_ln[(size_t)m * 512 + ct * 64 + cq * 16 + hh * 8] = o;
    }
}

// K7: LN2 fused stats+normalize, in place. y0 rows split across yB / yT.
__global__ __launch_bounds__(256) void ln2_fuse_k(ushort* __restrict__ yB,
                                                  ushort* __restrict__ yT,
                                                  const float* __restrict__ g,
                                                  const float* __restrict__ beta) {
    int w = threadIdx.x >> 6, lane = threadIdx.x & 63;
    int row = blockIdx.x * 4 + w;
    ushort* base = (row < 8192) ? (yB + (size_t)row * 512)
                                : (yT + (size_t)(row - 8192) * 512);
    ushort8 raw = *(ushort8*)&base[lane * 8];
    float v[8];
    float s = 0.f, ss = 0.f;
#pragma unroll
    for (int j = 0; j < 8; ++j) { v[j] = bf2f(raw[j]); s += v[j]; ss += v[j] * v[j]; }
#pragma unroll
    for (int off = 1; off < 64; off <<= 1) { s += __shfl_xor(s, off); ss += __shfl_xor(ss, off); }
    float mu = s * (1.0f / 512.0f);
    float rs = rsqrtf(ss * (1.0f / 512.0f) - mu * mu + 1e-6f);
    ushort8 o;
#pragma unroll
    for (int j = 0; j < 8; ++j) {
        int c = lane * 8 + j;
        o[j] = f2bb((v[j] - mu) * rs * g[c] + beta[c]);
    }
    *(ushort8*)&base[lane * 8] = o;
}

// ---------------------------------------------------------------------------
// m97-style MFMA GEMM: out[m,j] = sum_k A[m,k]*W[j,k]; A,W bf16 row-major.
// 128xBN tile, BK=32, 256 thr. LDS rows 64B unpadded (global_load_lds compat).
// BN=128: wave=64x64 quadrant (4x4 tiles). BN=64: wave=32x64 strip (2x4).
// XCD-band swizzle: whole grid is co-resident (4 blk/CU); default round-robin
// puts the x-blocks sharing one A-panel on 8 different L2s and thrashes each
// XCD's L2 (A working set 8MB > 4MB) -> 141MB FETCH vs ~10MB ideal. Remap so
// XCD (wgid&7) owns a contiguous y-band x all x-blocks: per-XCD A set = 1MB,
// A fetched once chip-wide, scatter-store sibling half-lines merge in L2.
// Bijective since all grids have nwg % 8 == 0.
// MODE 0 QKV : out bf16 permuted q/k/v [3][256][64][256]
// MODE 1 PROJ: out bf16 t2 = 2*(acc+bias)
// MODE 2 CONVT: scatter bf16 channels-last y0 (split base) + ct_b
// MODE 3 PW1 : out bf16 gelu(acc+bias), chunk-local rows [8192][2048]
// MODE 4 PW2 : out fp32 d_out = inp + acc + bias (global rows via m0)
// ---------------------------------------------------------------------------
struct GP {
    const ushort* A;
    const ushort* W;
    const float* bias;
    ushort* outB;
    ushort* outB2;
    float* outF;
    const float* inp;
    int K, m0;
};

template <int MODE, int BN>
__global__ __launch_bounds__(256) void mgemm_k(GP p) {
    constexpr int MT = (BN == 128) ? 4 : 2;   // 16-row m-tiles per wave
    constexpr int NT = 4;                     // 16-col n-tiles per wave
    __shared__ ushort As[128 * 32];           // 8 KiB, 64B rows
    __shared__ ushort Bs[BN * 32];
    int tid = threadIdx.x;
    int lane = tid & 63, w = tid >> 6;
    int lr = lane & 15, lq = lane >> 4;
    int mwoff = (BN == 128) ? (w >> 1) * 64 : w * 32;
    int nwoff = (BN == 128) ? (w & 1) * 64 : 0;
    // ---- XCD-band swizzle (bijective: nwg % 8 == 0 for all grids) ----
    int gx = gridDim.x;
    int wgid = blockIdx.y * gx + blockIdx.x;
    int cpx = (gx * gridDim.y) >> 3;          // blocks per XCD
    int swz = (wgid & 7) * cpx + (wgid >> 3);
    int bx = swz % gx, by = swz / gx;
    int mbase = by * 128, nbase = bx * BN;
    int lsub = lane >> 2, lcol = (lane & 3) * 8;   // staging: 16 rows x 4 chunks
    f32x4 acc[MT][NT] = {};

    for (int kb = 0; kb < p.K; kb += 32) {
        __syncthreads();
        // ---- stage A: 128 rows x 32 k, 2 issues per wave ----
#pragma unroll
        for (int i = 0; i < 2; ++i) {
            int row = w * 32 + i * 16;
            gl2lds16(p.A + (size_t)(mbase + row + lsub) * p.K + kb + lcol,
                     &As[row * 32]);
        }
        // ---- stage B: BN rows x 32 k ----
        if constexpr (BN == 128) {
#pragma unroll
            for (int i = 0; i < 2; ++i) {
                int row = w * 32 + i * 16;
                gl2lds16(p.W + (size_t)(nbase + row + lsub) * p.K + kb + lcol,
                         &Bs[row * 32]);
            }
        } else {
            int row = w * 16;
            gl2lds16(p.W + (size_t)(nbase + row + lsub) * p.K + kb + lcol,
                     &Bs[row * 32]);
        }
        __syncthreads();
        // ---- frags + MFMA ----
        short8 af[MT], bfr[NT];
#pragma unroll
        for (int t = 0; t < MT; ++t)
            af[t] = *(const short8*)&As[(mwoff + t * 16 + lr) * 32 + lq * 8];
#pragma unroll
        for (int t = 0; t < NT; ++t)
            bfr[t] = *(const short8*)&Bs[(nwoff + t * 16 + lr) * 32 + lq * 8];
#pragma unroll
        for (int i = 0; i < MT; ++i)
#pragma unroll
            for (int j = 0; j < NT; ++j)
                acc[i][j] = __builtin_amdgcn_mfma_f32_16x16x32_bf16(af[i], bfr[j], acc[i][j], 0, 0, 0);
    }

    // ---- epilogue: C/D col=lane&15, row=lq*4+r ----
    ushort* ybase = nullptr;
    if constexpr (MODE == 2)
        ybase = (mbase < 2048) ? p.outB : (p.outB2 - (size_t)8192 * 512);
#pragma unroll
    for (int ti = 0; ti < MT; ++ti) {
#pragma unroll
        for (int r = 0; r < 4; ++r) {
            int rg = mbase + mwoff + ti * 16 + lq * 4 + r;
#pragma unroll
            for (int tj = 0; tj < NT; ++tj) {
                int cg = nbase + nwoff + tj * 16 + lr;
                float v = acc[ti][tj][r];
                if constexpr (MODE == 0) {
                    int b = rg >> 8, n = rg & 255;
                    int sect = cg >> 9, h = (cg >> 6) & 7, d = cg & 63;
                    v += p.bias[cg];
                    p.outB[((size_t)(sect * 256 + b * 8 + h) * 64 + d) * 256 + n] = f2bb(v);
                } else if constexpr (MODE == 1) {
                    v = 2.0f * (v + p.bias[cg]);
                    p.outB[(size_t)rg * 512 + cg] = f2bb(v);
                } else if constexpr (MODE == 2) {
                    int o = cg >> 2, pp = (cg >> 1) & 1, qq = cg & 1;
                    int b = rg >> 8, rr = rg & 255, hh = rr >> 4, ww = rr & 15;
                    int pr = (b * 32 + 2 * hh + pp) * 32 + 2 * ww + qq;
                    v += p.bias[o];
                    ybase[(size_t)pr * 512 + o] = f2bb(v);
                } else if constexpr (MODE == 3) {
                    v += p.bias[cg];
                    float ge = 0.5f * v * (1.0f + erff(v * 0.70710678118654752f));
                    p.outB[(size_t)rg * 2048 + cg] = f2bb(ge);
                } else { // MODE 4
                    v += p.bias[cg];
                    int gm = p.m0 + rg;
                    int b = gm >> 10, hw = gm & 1023;
                    size_t idx = ((size_t)(b * 512 + cg)) * 1024 + hw;
                    p.outF[idx] = p.inp[idx] + v;
                }
            }
        }
    }
}

// ---------------------------------------------------------------------------
// K5: cosine attention per (b,h). qkvp bf16 [3][256][64][256].
// ---------------------------------------------------------------------------
__global__ __launch_bounds__(256) void attn_k(const ushort* __restrict__ qkvp,
                                              const float* __restrict__ mask_u,
                                              const float* __restrict__ temp,
                                              ushort* __restrict__ attn_out) {
    __shared__ float bufA[64 * 65];
    __shared__ float bufB[64 * 65];
    __shared__ float Sb[64 * 65];
    __shared__ float fq[64], fk[64];
    int tid = threadIdx.x;
    int bh = blockIdx.x;
    int b = bh >> 3, h = bh & 7;
    const ushort* q = qkvp + (size_t)bh * 16384;
    const ushort* k = qkvp + 4194304 + (size_t)bh * 16384;
    const ushort* v = qkvp + 8388608 + (size_t)bh * 16384;
    int wv = tid >> 6, lane = tid & 63;

    for (int rr = 0; rr < 16; ++rr) {
        int row = wv * 16 + rr;
        float s = 0.f;
#pragma unroll
        for (int i = 0; i < 4; ++i) { float xv = bf2f(q[row * 256 + lane + i * 64]); s += xv * xv; }
#pragma unroll
        for (int off = 32; off; off >>= 1) s += __shfl_down(s, off);
        if (lane == 0) fq[row] = 1.0f / fmaxf(sqrtf(s), 1e-12f);
        s = 0.f;
#pragma unroll
        for (int i = 0; i < 4; ++i) { float xv = bf2f(k[row * 256 + lane + i * 64]); s += xv * xv; }
#pragma unroll
        for (int off = 32; off; off >>= 1) s += __shfl_down(s, off);
        if (lane == 0) fk[row] = 1.0f / fmaxf(sqrtf(s), 1e-12f);
    }
    __syncthreads();

    int tx = tid & 15, ty = tid >> 4;
    float acc[4][4] = {};
    for (int nb = 0; nb < 256; nb += 64) {
        __syncthreads();
#pragma unroll
        for (int it = 0; it < 16; ++it) {
            int f = it * 256 + tid;
            int d = f >> 6, n = f & 63;
            bufA[d * 65 + n] = bf2f(q[d * 256 + nb + n]);
            bufB[d * 65 + n] = bf2f(k[d * 256 + nb + n]);
        }
        __syncthreads();
#pragma unroll 8
        for (int kk = 0; kk < 64; ++kk) {
            float a[4], bb[4];
#pragma unroll
            for (int i = 0; i < 4; ++i) a[i] = bufA[(ty * 4 + i) * 65 + kk];
#pragma unroll
            for (int j = 0; j < 4; ++j) bb[j] = bufB[(tx * 4 + j) * 65 + kk];
#pragma unroll
            for (int i = 0; i < 4; ++i)
#pragma unroll
                for (int j = 0; j < 4; ++j) acc[i][j] += a[i] * bb[j];
        }
    }
    float tv = temp[h];
    __syncthreads();
#pragma unroll
    for (int i = 0; i < 4; ++i) {
        int d = ty * 4 + i;
#pragma unroll
        for (int j = 0; j < 4; ++j) {
            int e = tx * 4 + j;
            float sc = acc[i][j] * fq[d] * fk[e] * tv;
            float mu = mask_u[((size_t)bh * 64 + d) * 64 + e];
            if (mu < 0.2f) sc -= 1e12f;
            Sb[d * 65 + e] = sc;
        }
    }
    __syncthreads();

    {
        int row = tid >> 2, sub = tid & 3;
        float ev[16];
        float mx = -INFINITY;
#pragma unroll
        for (int i = 0; i < 16; ++i) { float s = Sb[row * 65 + sub * 16 + i]; ev[i] = s; mx = fmaxf(mx, s); }
        mx = fmaxf(mx, __shfl_xor(mx, 1));
        mx = fmaxf(mx, __shfl_xor(mx, 2));
        float sum = 0.f;
#pragma unroll
        for (int i = 0; i < 16; ++i) { ev[i] = expf(ev[i] - mx); sum += ev[i]; }
        sum += __shfl_xor(sum, 1);
        sum += __shfl_xor(sum, 2);
        float inv = 1.0f / sum;
#pragma unroll
        for (int i = 0; i < 16; ++i) Sb[row * 65 + sub * 16 + i] = ev[i] * inv;
    }
    __syncthreads();

    for (int nb = 0; nb < 256; nb += 64) {
        __syncthreads();
#pragma unroll
        for (int it = 0; it < 16; ++it) {
            int f = it * 256 + tid;
            int e = f >> 6, n = f & 63;
            bufA[e * 65 + n] = bf2f(v[e * 256 + nb + n]);
        }
        __syncthreads();
        float o[4][4] = {};
#pragma unroll 8
        for (int kk = 0; kk < 64; ++kk) {
            float a[4], bb[4];
#pragma unroll
            for (int i = 0; i < 4; ++i) a[i] = Sb[(ty * 4 + i) * 65 + kk];
#pragma unroll
            for (int j = 0; j < 4; ++j) bb[j] = bufA[kk * 65 + tx * 4 + j];
#pragma unroll
            for (int i = 0; i < 4; ++i)
#pragma unroll
                for (int j = 0; j < 4; ++j) o[i][j] += a[i] * bb[j];
        }
#pragma unroll
        for (int j = 0; j < 4; ++j) {
            int n = nb + tx * 4 + j;
            size_t base = ((size_t)(b * 256 + n)) * 512 + h * 64 + ty * 4;
#pragma unroll
            for (int i = 0; i < 4; ++i) attn_out[base + i] = f2bb(o[i][j]);
        }
    }
}

// ---------------------------------------------------------------------------
extern "C" void kernel_launch(void* const* d_in, const int* in_sizes, int n_in,
                              void* d_out, int out_size, void* d_ws, size_t ws_size,
                              hipStream_t stream) {
    const float* x      = (const float*)d_in[0];
    const float* mask_u = (const float*)d_in[1];
    const float* dw_w   = (const float*)d_in[2];
    const float* dw_b   = (const float*)d_in[3];
    const float* ln1_g  = (const float*)d_in[4];
    const float* ln1_b  = (const float*)d_in[5];
    const float* qkv_w  = (const float*)d_in[6];
    const float* qkv_b  = (const float*)d_in[7];
    const float* temp   = (const float*)d_in[8];
    const float* proj_w = (const float*)d_in[9];
    const float* proj_b = (const float*)d_in[10];
    const float* ct_w   = (const float*)d_in[11];
    const float* ct_b   = (const float*)d_in[12];
    const float* ln2_g  = (const float*)d_in[13];
    const float* ln2_b  = (const float*)d_in[14];
    const float* pw1_w  = (const float*)d_in[15];
    const float* pw1_b  = (const float*)d_in[16];
    const float* pw2_w  = (const float*)d_in[17];
    const float* pw2_b  = (const float*)d_in[18];

    char* wsb = (char*)d_ws;
    float* mean1 = (float*)wsb;
    float* rstd1 = mean1 + 8192;
    float* mean2 = rstd1 + 8192;     // unused now (ln2 fused) but reserved
    float* rstd2 = mean2 + 32768;
    (void)mean2; (void)rstd2;
    ushort* wq = (ushort*)(wsb + 524288);
    ushort* wp = wq + 786432;
    ushort* wc = wp + 262144;
    ushort* w1 = wc + 1048576;
    ushort* w2 = w1 + 1048576;
    ushort* xp     = (ushort*)(wsb + 8912896);   // region A: 8 MiB
    ushort* t2     = xp;                         // A reuse (xp dead after ln1_apply+qkv)
    ushort* a_ln   = (ushort*)(wsb + 17301504);  // region Br: 8 MiB
    ushort* yB     = a_ln;                       // Br reuse: y0 rows 0..8191
    ushort* qkvp   = (ushort*)(wsb + 25690112);  // region CD: 24 MiB
    ushort* attn_o = (ushort*)(wsb + 50855936);  // CD tail: 8 MiB
    ushort* h1c    = qkvp;                       // CD reuse: [8192][2048] 32 MiB
    ushort* yT     = (ushort*)(wsb + 59244544);  // region T: 24 MiB, rows 8192..32767

    // 0. weight conversions
    cvtw_k<<<768,  256, 0, stream>>>(qkv_w,  wq, 196608);
    cvtw_k<<<256,  256, 0, stream>>>(proj_w, wp, 65536);
    cvtw_k<<<1024, 256, 0, stream>>>(pw1_w,  w1, 262144);
    cvtw_k<<<1024, 256, 0, stream>>>(pw2_w,  w2, 262144);
    cvtt_k<<<dim3(64, 16), 256, 0, stream>>>(ct_w, wc);
    // 1. depthwise conv + residual + avgpool
    dwpool_k<<<32 * 512, 256, 0, stream>>>(x, dw_w, dw_b, xp);
    // 2-3. LN1 stats + apply/transpose -> a_ln
    ln1_stats_k<<<128, 256, 0, stream>>>(xp, mean1, rstd1);
    ln1_apply_k<<<1024, 256, 0, stream>>>(xp, mean1, rstd1, ln1_g, ln1_b, a_ln);
    // 4. QKV gemm -> qkvp (permuted)
    {
        GP p{}; p.A = a_ln; p.W = wq; p.bias = qkv_b; p.outB = qkvp; p.K = 512;
        mgemm_k<0, 128><<<dim3(12, 64), 256, 0, stream>>>(p);
    }
    // 5. attention
    attn_k<<<256, 256, 0, stream>>>(qkvp, mask_u, temp, attn_o);
    // 6. proj gemm (x2) -> t2
    {
        GP p{}; p.A = attn_o; p.W = wp; p.bias = proj_b; p.outB = t2; p.K = 512;
        mgemm_k<1, 128><<<dim3(4, 64), 256, 0, stream>>>(p);
    }
    // 7. convT gemm -> y0 (split yB/yT), channels-last
    {
        GP p{}; p.A = t2; p.W = wc; p.bias = ct_b;
        p.outB = yB; p.outB2 = yT; p.K = 512;
        mgemm_k<2, 128><<<dim3(16, 64), 256, 0, stream>>>(p);
    }
    // 8. LN2 fused stats+normalize in place
    ln2_fuse_k<<<8192, 256, 0, stream>>>(yB, yT, ln2_g, ln2_b);
    // 9. MLP in 4 chunks of 8192 rows
    for (int c = 0; c < 4; ++c) {
        int m0 = c * 8192;
        const ushort* yChunk = (c == 0) ? yB : (yT + (size_t)(m0 - 8192) * 512);
        {
            GP p{}; p.A = yChunk; p.W = w1; p.bias = pw1_b; p.outB = h1c; p.K = 512;
            mgemm_k<3, 128><<<dim3(16, 64), 256, 0, stream>>>(p);
        }
        {
            GP p{}; p.A = h1c; p.W = w2; p.bias = pw2_b;
            p.outF = (float*)d_out; p.inp = x; p.K = 2048; p.m0 = m0;
            mgemm_k<4, 64><<<dim3(8, 64), 256, 0, stream>>>(p);
        }
    }
}

// Round 2
// 714.938 us; speedup vs baseline: 1.0296x; 1.0131x over previous
//
#include <hip/hip_runtime.h>
#include <hip/hip_bf16.h>
#include <math.h>

typedef unsigned short ushort;
typedef __attribute__((ext_vector_type(8))) short short8;
typedef __attribute__((ext_vector_type(8))) unsigned short ushort8;
typedef __attribute__((ext_vector_type(4))) unsigned short ushort4v;
typedef __attribute__((ext_vector_type(4))) float f32x4;

__device__ __forceinline__ ushort f2bb(float v) {
    return __builtin_bit_cast(ushort, __float2bfloat16(v));
}
__device__ __forceinline__ float bf2f(ushort u) {
    return __bfloat162float(__builtin_bit_cast(__hip_bfloat16, u));
}
// async global->LDS 16B/lane; LDS dest = wave-uniform base + lane*16
__device__ __forceinline__ void gl2lds16(const ushort* g, ushort* l) {
    __builtin_amdgcn_global_load_lds(
        (const __attribute__((address_space(1))) unsigned int*)g,
        (__attribute__((address_space(3))) unsigned int*)l, 16, 0, 0);
}

// ---------------------------------------------------------------------------
// B=32, C=512, H=W=32, NH=8, dh=64, N=256 pooled, hidden=2048.
// GEMMs: m97-style — global_load_lds staging, BK=32, 16x16x32 bf16 MFMA.
// r2 changes:
//  * K-tile chunk XOR-swizzle (rule #21: permute global SOURCE chunk per row,
//    XOR same on ds_read) kills the 8-way bank conflict on frag reads
//    (3.1M conflict cycles/dispatch -> ~0).
//  * LDS-restaged vectorized epilogues: all modes now emit full-line
//    short8/float4 stores (was per-lane 2B/4B scatter -> WRITE 3x ideal + RFO).
// ---------------------------------------------------------------------------

__global__ __launch_bounds__(256) void cvtw_k(const float* __restrict__ in,
                                              ushort* __restrict__ out, int n4) {
    int i = blockIdx.x * 256 + threadIdx.x;
    if (i >= n4) return;
    float4 v = ((const float4*)in)[i];
    ushort4v o;
    o.x = f2bb(v.x); o.y = f2bb(v.y); o.z = f2bb(v.z); o.w = f2bb(v.w);
    ((ushort4v*)out)[i] = o;
}

// ct_w [512][2048] fp32 -> [2048][512] bf16
__global__ __launch_bounds__(256) void cvtt_k(const float* __restrict__ in,
                                              ushort* __restrict__ out) {
    __shared__ float tl[32][33];
    int c0 = blockIdx.y * 32, j0 = blockIdx.x * 32;
    int tr = threadIdx.x >> 5, tc = threadIdx.x & 31;
#pragma unroll
    for (int p4 = 0; p4 < 4; ++p4)
        tl[tr + p4 * 8][tc] = in[(size_t)(c0 + tr + p4 * 8) * 2048 + j0 + tc];
    __syncthreads();
#pragma unroll
    for (int p4 = 0; p4 < 4; ++p4)
        out[(size_t)(j0 + tr + p4 * 8) * 512 + c0 + tc] = f2bb(tl[tc][tr + p4 * 8]);
}

// K1: depthwise 3x3 + bias + residual + 2x2 avgpool -> xp bf16 [B,C,16,16]
__global__ __launch_bounds__(256) void dwpool_k(const float* __restrict__ x,
                                                const float* __restrict__ dww,
                                                const float* __restrict__ dwb,
                                                ushort* __restrict__ xp) {
    int bc = blockIdx.x;
    int c = bc & 511;
    __shared__ float tile[32][33];
    __shared__ float w9[9];
    const float* xb = x + (size_t)bc * 1024;
    int tid = threadIdx.x;
    for (int i = tid; i < 1024; i += 256) tile[i >> 5][i & 31] = xb[i];
    if (tid < 9) w9[tid] = dww[c * 9 + tid];
    __syncthreads();
    float bv = dwb[c];
    int ph = tid >> 4, pw = tid & 15;
    float s = 0.f;
#pragma unroll
    for (int dy = 0; dy < 2; ++dy) {
#pragma unroll
        for (int dx = 0; dx < 2; ++dx) {
            int hh = 2 * ph + dy, ww = 2 * pw + dx;
            float a = bv + tile[hh][ww];
#pragma unroll
            for (int ky = 0; ky < 3; ++ky) {
                int yy = hh + ky - 1;
                if (yy < 0 || yy > 31) continue;
#pragma unroll
                for (int kx = 0; kx < 3; ++kx) {
                    int xx = ww + kx - 1;
                    if (xx < 0 || xx > 31) continue;
                    a += w9[ky * 3 + kx] * tile[yy][xx];
                }
            }
            s += a;
        }
    }
    xp[(size_t)bc * 256 + tid] = f2bb(0.25f * s);
}

// K2: LN1 stats per token over C=512; xp bf16 [b][c][n]
__global__ __launch_bounds__(256) void ln1_stats_k(const ushort* __restrict__ xp,
                                                   float* __restrict__ m1,
                                                   float* __restrict__ r1) {
    __shared__ float sh_s[4][64], sh_q[4][64];
    int blk = blockIdx.x;
    int b = blk >> 2;
    int n0 = (blk & 3) * 64;
    int t = threadIdx.x & 63, w = threadIdx.x >> 6;
    float s = 0.f, ss = 0.f;
    for (int i = 0; i < 128; ++i) {
        int c = w * 128 + i;
        float v = bf2f(xp[(size_t)(b * 512 + c) * 256 + n0 + t]);
        s += v; ss += v * v;
    }
    sh_s[w][t] = s; sh_q[w][t] = ss;
    __syncthreads();
    if (w == 0) {
        s  = sh_s[0][t] + sh_s[1][t] + sh_s[2][t] + sh_s[3][t];
        ss = sh_q[0][t] + sh_q[1][t] + sh_q[2][t] + sh_q[3][t];
        float m = s * (1.0f / 512.0f);
        m1[b * 256 + n0 + t] = m;
        r1[b * 256 + n0 + t] = rsqrtf(ss * (1.0f / 512.0f) - m * m + 1e-6f);
    }
}

// K3: LN1 apply + transpose: xp [b][c][n] -> a_ln [m][c] bf16 normalized
__global__ __launch_bounds__(256) void ln1_apply_k(const ushort* __restrict__ xp,
                                                   const float* __restrict__ m1,
                                                   const float* __restrict__ r1,
                                                   const float* __restrict__ g,
                                                   const float* __restrict__ beta,
                                                   ushort* __restrict__ a_ln) {
    __shared__ float tl[64][66];
    int blk = blockIdx.x;                 // b*32 + ct*4 + nt
    int b = blk >> 5, ct = (blk >> 2) & 7, nt = blk & 3;
    int t = threadIdx.x;
    int rq = t >> 6, nl = t & 63;
#pragma unroll
    for (int i = 0; i < 16; ++i) {
        int r = rq * 16 + i;
        int c = ct * 64 + r;
        tl[r][nl] = bf2f(xp[(size_t)(b * 512 + c) * 256 + nt * 64 + nl]);
    }
    __syncthreads();
    int r2 = t >> 2, cq = t & 3;
    int m = b * 256 + nt * 64 + r2;
    float mu = m1[m], rs = r1[m];
#pragma unroll
    for (int hh = 0; hh < 2; ++hh) {
        ushort8 o;
#pragma unroll
        for (int j = 0; j < 8; ++j) {
            int cl = cq * 16 + hh * 8 + j;
            int c = ct * 64 + cl;
            o[j] = f2bb((tl[cl][r2] - mu) * rs * g[c] + beta[c]);
        }
        *(ushort8*)&a_ln[(size_t)m * 512 + ct * 64 + cq * 16 + hh * 8] = o;
    }
}

// K7: LN2 fused stats+normalize, in place. y0 rows split across yB / yT.
__global__ __launch_bounds__(256) void ln2_fuse_k(ushort* __restrict__ yB,
                                                  ushort* __restrict__ yT,
                                                  const float* __restrict__ g,
                                                  const float* __restrict__ beta) {
    int w = threadIdx.x >> 6, lane = threadIdx.x & 63;
    int row = blockIdx.x * 4 + w;
    ushort* base = (row < 8192) ? (yB + (size_t)row * 512)
                                : (yT + (size_t)(row - 8192) * 512);
    ushort8 raw = *(ushort8*)&base[lane * 8];
    float v[8];
    float s = 0.f, ss = 0.f;
#pragma unroll
    for (int j = 0; j < 8; ++j) { v[j] = bf2f(raw[j]); s += v[j]; ss += v[j] * v[j]; }
#pragma unroll
    for (int off = 1; off < 64; off <<= 1) { s += __shfl_xor(s, off); ss += __shfl_xor(ss, off); }
    float mu = s * (1.0f / 512.0f);
    float rs = rsqrtf(ss * (1.0f / 512.0f) - mu * mu + 1e-6f);
    ushort8 o;
#pragma unroll
    for (int j = 0; j < 8; ++j) {
        int c = lane * 8 + j;
        o[j] = f2bb((v[j] - mu) * rs * g[c] + beta[c]);
    }
    *(ushort8*)&base[lane * 8] = o;
}

// ---------------------------------------------------------------------------
// m97-style MFMA GEMM: out[m,j] = sum_k A[m,k]*W[j,k]; A,W bf16 row-major.
// 128xBN tile, BK=32, 256 thr. K-chunk XOR swizzle both sides (see header).
// Epilogues restage the 128xBN tile through LDS and emit full-line stores.
// MODE 0 QKV : out bf16 permuted q/k/v [3][256][64][256] (n-fast)
// MODE 1 PROJ: out bf16 t2 = 2*(acc+bias), row-major LD=512
// MODE 2 CONVT: bf16 channels-last y0 (split base) + ct_b, 64B/pixel chunks
// MODE 3 PW1 : out bf16 gelu(acc+bias), row-major LD=2048
// MODE 4 PW2 : out fp32 d_out = inp + acc + bias (hw-fast, float4 ld/st)
// ---------------------------------------------------------------------------
struct GP {
    const ushort* A;
    const ushort* W;
    const float* bias;
    ushort* outB;
    ushort* outB2;
    float* outF;
    const float* inp;
    int K, m0;
};

template <int MODE, int BN>
__global__ __launch_bounds__(256) void mgemm_k(GP p) {
    constexpr int MT = (BN == 128) ? 4 : 2;   // 16-row m-tiles per wave
    constexpr int NT = 4;                     // 16-col n-tiles per wave
    constexpr int SMEM_BYTES = (MODE == 2) ? 20480 : ((MODE == 4) ? 16896 : 16384);
    __shared__ __align__(16) char smem[SMEM_BYTES];
    ushort* As = (ushort*)smem;               // [128][32] us, chunk-swizzled
    ushort* Bs = As + 128 * 32;               // [BN][32] us
    int tid = threadIdx.x;
    int lane = tid & 63, w = tid >> 6;
    int lr = lane & 15, lq = lane >> 4;
    int mwoff = (BN == 128) ? (w >> 1) * 64 : w * 32;
    int nwoff = (BN == 128) ? (w & 1) * 64 : 0;
    // ---- XCD-band swizzle (bijective: nwg % 8 == 0 for all grids) ----
    int gx = gridDim.x;
    int wgid = blockIdx.y * gx + blockIdx.x;
    int cpx = (gx * gridDim.y) >> 3;          // blocks per XCD
    int swz = (wgid & 7) * cpx + (wgid >> 3);
    int bx = swz % gx, by = swz / gx;
    int mbase = by * 128, nbase = bx * BN;
    // staging: 16 rows x 4 chunks; source chunk permuted so linear LDS dest
    // holds the swizzled layout (rule #21)
    int lsub = lane >> 2;
    int cchunk = (lane & 3) ^ ((lsub >> 1) & 3);
    int lcol = cchunk * 8;
    int physc = lq ^ ((lr >> 1) & 3);         // frag-read phys chunk
    f32x4 acc[MT][NT] = {};

    for (int kb = 0; kb < p.K; kb += 32) {
        __syncthreads();
#pragma unroll
        for (int i = 0; i < 2; ++i) {
            int row = w * 32 + i * 16;
            gl2lds16(p.A + (size_t)(mbase + row + lsub) * p.K + kb + lcol,
                     &As[row * 32]);
        }
        if constexpr (BN == 128) {
#pragma unroll
            for (int i = 0; i < 2; ++i) {
                int row = w * 32 + i * 16;
                gl2lds16(p.W + (size_t)(nbase + row + lsub) * p.K + kb + lcol,
                         &Bs[row * 32]);
            }
        } else {
            int row = w * 16;
            gl2lds16(p.W + (size_t)(nbase + row + lsub) * p.K + kb + lcol,
                     &Bs[row * 32]);
        }
        __syncthreads();
        short8 af[MT], bfr[NT];
#pragma unroll
        for (int t = 0; t < MT; ++t)
            af[t] = *(const short8*)&As[(mwoff + t * 16 + lr) * 32 + physc * 8];
#pragma unroll
        for (int t = 0; t < NT; ++t)
            bfr[t] = *(const short8*)&Bs[(nwoff + t * 16 + lr) * 32 + physc * 8];
#pragma unroll
        for (int i = 0; i < MT; ++i)
#pragma unroll
            for (int j = 0; j < NT; ++j)
                acc[i][j] = __builtin_amdgcn_mfma_f32_16x16x32_bf16(af[i], bfr[j], acc[i][j], 0, 0, 0);
    }

    // ================= epilogues (LDS restage -> vector stores) =============
    if constexpr (MODE == 1 || MODE == 3) {
        // row-major bf16 out, cols fast. eb [128][64] us, chunk^(row&7) swizzle.
        const size_t LD = (MODE == 1) ? 512 : 2048;
        ushort* eb = (ushort*)smem;
#pragma unroll
        for (int h = 0; h < 2; ++h) {
            __syncthreads();
            if ((w & 1) == h) {
#pragma unroll
                for (int ti = 0; ti < MT; ++ti)
#pragma unroll
                    for (int tj = 0; tj < NT; ++tj)
#pragma unroll
                        for (int r = 0; r < 4; ++r) {
                            int row = mwoff + ti * 16 + lq * 4 + r;     // 0..127
                            int colh = tj * 16 + lr;                    // 0..63
                            float v = acc[ti][tj][r] + p.bias[nbase + h * 64 + colh];
                            if constexpr (MODE == 1) v *= 2.0f;
                            else v = 0.5f * v * (1.0f + erff(v * 0.70710678118654752f));
                            int ph = (colh >> 3) ^ (row & 7);
                            eb[row * 64 + ph * 8 + (colh & 7)] = f2bb(v);
                        }
            }
            __syncthreads();
#pragma unroll
            for (int i = 0; i < 4; ++i) {
                int row = i * 32 + (tid >> 3);
                int ch = tid & 7;
                int pch = ch ^ (row & 7);
                short8 d = *(short8*)&eb[row * 64 + pch * 8];
                *(short8*)&p.outB[(size_t)(mbase + row) * LD + nbase + h * 64 + ch * 8] = d;
            }
        }
    } else if constexpr (MODE == 0) {
        // QKV permuted out, n-fast. eb [32 c][136 row-us].
        ushort* eb = (ushort*)smem;
        int b = mbase >> 8, n0 = mbase & 255;
#pragma unroll
        for (int pc = 0; pc < 4; ++pc) {
            __syncthreads();
            if ((w & 1) == (pc >> 1)) {
                int tjb = (pc & 1) * 2;
#pragma unroll
                for (int ti = 0; ti < MT; ++ti)
#pragma unroll
                    for (int tj2 = 0; tj2 < 2; ++tj2)
#pragma unroll
                        for (int r = 0; r < 4; ++r) {
                            int tj = tjb + tj2;
                            int row = mwoff + ti * 16 + lq * 4 + r;
                            int cl = tj2 * 16 + lr;                    // 0..31
                            float v = acc[ti][tj][r] + p.bias[nbase + pc * 32 + cl];
                            eb[cl * 136 + row] = f2bb(v);
                        }
            }
            __syncthreads();
#pragma unroll
            for (int i = 0; i < 2; ++i) {
                int dl = (tid >> 4) + 16 * i;                          // 0..31
                int ch = tid & 15;                                     // 8-n chunk
                short8 d = *(short8*)&eb[dl * 136 + ch * 8];
                int cg = nbase + pc * 32 + dl;
                int sect = cg >> 9, hh = (cg >> 6) & 7, dd = cg & 63;
                size_t addr = ((size_t)(sect * 256 + b * 8 + hh) * 64 + dd) * 256 + n0 + ch * 8;
                *(short8*)&p.outB[addr] = d;
            }
        }
    } else if constexpr (MODE == 2) {
        // convT pixel scatter -> eb [256 pix][40 us], 64B/pixel stores.
        ushort* eb = (ushort*)smem;
        ushort* ybase = (mbase < 2048) ? p.outB : (p.outB2 - (size_t)8192 * 512);
        int obase = nbase >> 2;
#pragma unroll
        for (int hf = 0; hf < 2; ++hf) {
            __syncthreads();
            if ((w >> 1) == hf) {
#pragma unroll
                for (int ti = 0; ti < MT; ++ti)
#pragma unroll
                    for (int tj = 0; tj < NT; ++tj)
#pragma unroll
                        for (int r = 0; r < 4; ++r) {
                            int rl = (mwoff - hf * 64) + ti * 16 + lq * 4 + r; // 0..63
                            int cgl = nwoff + tj * 16 + lr;                    // 0..127
                            int o_l = cgl >> 2, pp = (cgl >> 1) & 1, qq = cgl & 1;
                            int pix = ((rl >> 4) * 2 + pp) * 32 + (rl & 15) * 2 + qq;
                            float v = acc[ti][tj][r] + p.bias[obase + o_l];
                            eb[pix * 40 + o_l] = f2bb(v);
                        }
            }
            __syncthreads();
            int hhbase = ((mbase & 255) >> 4) + hf * 4;
            int prb = (mbase >> 8) * 32 + 2 * hhbase;
#pragma unroll
            for (int i = 0; i < 4; ++i) {
                int pix = i * 64 + (tid >> 2);
                int ch = tid & 3;
                short8 d = *(short8*)&eb[pix * 40 + ch * 8];
                int pr = (prb + (pix >> 5)) * 32 + (pix & 31);
                *(short8*)&ybase[(size_t)pr * 512 + obase + ch * 8] = d;
            }
        }
    } else {
        // MODE 4: fp32 out, hw(=row)-fast. ef [32 c][132 row-f32], float4 I/O.
        float* ef = (float*)smem;
        int gm0 = p.m0 + mbase;
        int b = gm0 >> 10, hw0 = gm0 & 1023;
#pragma unroll
        for (int pc = 0; pc < 2; ++pc) {
            __syncthreads();
#pragma unroll
            for (int ti = 0; ti < MT; ++ti)
#pragma unroll
                for (int tj2 = 0; tj2 < 2; ++tj2)
#pragma unroll
                    for (int r = 0; r < 4; ++r) {
                        int tj = pc * 2 + tj2;
                        int row = mwoff + ti * 16 + lq * 4 + r;        // 0..127
                        int cl = tj2 * 16 + lr;                        // 0..31
                        ef[cl * 132 + row] = acc[ti][tj][r] + p.bias[nbase + pc * 32 + cl];
                    }
            __syncthreads();
#pragma unroll
            for (int i = 0; i < 4; ++i) {
                int cl = (tid >> 5) + 8 * i;                           // 0..31
                int ck = tid & 31;                                     // 4-row chunk
                float4 v4 = *(float4*)&ef[cl * 132 + ck * 4];
                int c = nbase + pc * 32 + cl;
                size_t idx = ((size_t)(b * 512 + c)) * 1024 + hw0 + ck * 4;
                float4 xin = *(const float4*)&p.inp[idx];
                float4 o4;
                o4.x = xin.x + v4.x; o4.y = xin.y + v4.y;
                o4.z = xin.z + v4.z; o4.w = xin.w + v4.w;
                *(float4*)&p.outF[idx] = o4;
            }
        }
    }
}

// ---------------------------------------------------------------------------
// K5: cosine attention per (b,h). qkvp bf16 [3][256][64][256].
// ---------------------------------------------------------------------------
__global__ __launch_bounds__(256) void attn_k(const ushort* __restrict__ qkvp,
                                              const float* __restrict__ mask_u,
                                              const float* __restrict__ temp,
                                              ushort* __restrict__ attn_out) {
    __shared__ float bufA[64 * 65];
    __shared__ float bufB[64 * 65];
    __shared__ float Sb[64 * 65];
    __shared__ float fq[64], fk[64];
    int tid = threadIdx.x;
    int bh = blockIdx.x;
    int b = bh >> 3, h = bh & 7;
    const ushort* q = qkvp + (size_t)bh * 16384;
    const ushort* k = qkvp + 4194304 + (size_t)bh * 16384;
    const ushort* v = qkvp + 8388608 + (size_t)bh * 16384;
    int wv = tid >> 6, lane = tid & 63;

    for (int rr = 0; rr < 16; ++rr) {
        int row = wv * 16 + rr;
        float s = 0.f;
#pragma unroll
        for (int i = 0; i < 4; ++i) { float xv = bf2f(q[row * 256 + lane + i * 64]); s += xv * xv; }
#pragma unroll
        for (int off = 32; off; off >>= 1) s += __shfl_down(s, off);
        if (lane == 0) fq[row] = 1.0f / fmaxf(sqrtf(s), 1e-12f);
        s = 0.f;
#pragma unroll
        for (int i = 0; i < 4; ++i) { float xv = bf2f(k[row * 256 + lane + i * 64]); s += xv * xv; }
#pragma unroll
        for (int off = 32; off; off >>= 1) s += __shfl_down(s, off);
        if (lane == 0) fk[row] = 1.0f / fmaxf(sqrtf(s), 1e-12f);
    }
    __syncthreads();

    int tx = tid & 15, ty = tid >> 4;
    float acc[4][4] = {};
    for (int nb = 0; nb < 256; nb += 64) {
        __syncthreads();
#pragma unroll
        for (int it = 0; it < 16; ++it) {
            int f = it * 256 + tid;
            int d = f >> 6, n = f & 63;
            bufA[d * 65 + n] = bf2f(q[d * 256 + nb + n]);
            bufB[d * 65 + n] = bf2f(k[d * 256 + nb + n]);
        }
        __syncthreads();
#pragma unroll 8
        for (int kk = 0; kk < 64; ++kk) {
            float a[4], bb[4];
#pragma unroll
            for (int i = 0; i < 4; ++i) a[i] = bufA[(ty * 4 + i) * 65 + kk];
#pragma unroll
            for (int j = 0; j < 4; ++j) bb[j] = bufB[(tx * 4 + j) * 65 + kk];
#pragma unroll
            for (int i = 0; i < 4; ++i)
#pragma unroll
                for (int j = 0; j < 4; ++j) acc[i][j] += a[i] * bb[j];
        }
    }
    float tv = temp[h];
    __syncthreads();
#pragma unroll
    for (int i = 0; i < 4; ++i) {
        int d = ty * 4 + i;
#pragma unroll
        for (int j = 0; j < 4; ++j) {
            int e = tx * 4 + j;
            float sc = acc[i][j] * fq[d] * fk[e] * tv;
            float mu = mask_u[((size_t)bh * 64 + d) * 64 + e];
            if (mu < 0.2f) sc -= 1e12f;
            Sb[d * 65 + e] = sc;
        }
    }
    __syncthreads();

    {
        int row = tid >> 2, sub = tid & 3;
        float ev[16];
        float mx = -INFINITY;
#pragma unroll
        for (int i = 0; i < 16; ++i) { float s = Sb[row * 65 + sub * 16 + i]; ev[i] = s; mx = fmaxf(mx, s); }
        mx = fmaxf(mx, __shfl_xor(mx, 1));
        mx = fmaxf(mx, __shfl_xor(mx, 2));
        float sum = 0.f;
#pragma unroll
        for (int i = 0; i < 16; ++i) { ev[i] = expf(ev[i] - mx); sum += ev[i]; }
        sum += __shfl_xor(sum, 1);
        sum += __shfl_xor(sum, 2);
        float inv = 1.0f / sum;
#pragma unroll
        for (int i = 0; i < 16; ++i) Sb[row * 65 + sub * 16 + i] = ev[i] * inv;
    }
    __syncthreads();

    for (int nb = 0; nb < 256; nb += 64) {
        __syncthreads();
#pragma unroll
        for (int it = 0; it < 16; ++it) {
            int f = it * 256 + tid;
            int e = f >> 6, n = f & 63;
            bufA[e * 65 + n] = bf2f(v[e * 256 + nb + n]);
        }
        __syncthreads();
        float o[4][4] = {};
#pragma unroll 8
        for (int kk = 0; kk < 64; ++kk) {
            float a[4], bb[4];
#pragma unroll
            for (int i = 0; i < 4; ++i) a[i] = Sb[(ty * 4 + i) * 65 + kk];
#pragma unroll
            for (int j = 0; j < 4; ++j) bb[j] = bufA[kk * 65 + tx * 4 + j];
#pragma unroll
            for (int i = 0; i < 4; ++i)
#pragma unroll
                for (int j = 0; j < 4; ++j) o[i][j] += a[i] * bb[j];
        }
#pragma unroll
        for (int j = 0; j < 4; ++j) {
            int n = nb + tx * 4 + j;
            size_t base = ((size_t)(b * 256 + n)) * 512 + h * 64 + ty * 4;
#pragma unroll
            for (int i = 0; i < 4; ++i) attn_out[base + i] = f2bb(o[i][j]);
        }
    }
}

// ---------------------------------------------------------------------------
extern "C" void kernel_launch(void* const* d_in, const int* in_sizes, int n_in,
                              void* d_out, int out_size, void* d_ws, size_t ws_size,
                              hipStream_t stream) {
    const float* x      = (const float*)d_in[0];
    const float* mask_u = (const float*)d_in[1];
    const float* dw_w   = (const float*)d_in[2];
    const float* dw_b   = (const float*)d_in[3];
    const float* ln1_g  = (const float*)d_in[4];
    const float* ln1_b  = (const float*)d_in[5];
    const float* qkv_w  = (const float*)d_in[6];
    const float* qkv_b  = (const float*)d_in[7];
    const float* temp   = (const float*)d_in[8];
    const float* proj_w = (const float*)d_in[9];
    const float* proj_b = (const float*)d_in[10];
    const float* ct_w   = (const float*)d_in[11];
    const float* ct_b   = (const float*)d_in[12];
    const float* ln2_g  = (const float*)d_in[13];
    const float* ln2_b  = (const float*)d_in[14];
    const float* pw1_w  = (const float*)d_in[15];
    const float* pw1_b  = (const float*)d_in[16];
    const float* pw2_w  = (const float*)d_in[17];
    const float* pw2_b  = (const float*)d_in[18];

    char* wsb = (char*)d_ws;
    float* mean1 = (float*)wsb;
    float* rstd1 = mean1 + 8192;
    ushort* wq = (ushort*)(wsb + 524288);
    ushort* wp = wq + 786432;
    ushort* wc = wp + 262144;
    ushort* w1 = wc + 1048576;
    ushort* w2 = w1 + 1048576;
    ushort* xp     = (ushort*)(wsb + 8912896);   // region A: 8 MiB
    ushort* t2     = xp;                         // A reuse
    ushort* a_ln   = (ushort*)(wsb + 17301504);  // region Br: 8 MiB
    ushort* yB     = a_ln;                       // Br reuse: y0 rows 0..8191
    ushort* qkvp   = (ushort*)(wsb + 25690112);  // region CD: 24 MiB
    ushort* attn_o = (ushort*)(wsb + 50855936);  // CD tail: 8 MiB
    ushort* h1c    = qkvp;                       // CD reuse: [8192][2048] 32 MiB
    ushort* yT     = (ushort*)(wsb + 59244544);  // region T: 24 MiB

    // 0. weight conversions
    cvtw_k<<<768,  256, 0, stream>>>(qkv_w,  wq, 196608);
    cvtw_k<<<256,  256, 0, stream>>>(proj_w, wp, 65536);
    cvtw_k<<<1024, 256, 0, stream>>>(pw1_w,  w1, 262144);
    cvtw_k<<<1024, 256, 0, stream>>>(pw2_w,  w2, 262144);
    cvtt_k<<<dim3(64, 16), 256, 0, stream>>>(ct_w, wc);
    // 1. depthwise conv + residual + avgpool
    dwpool_k<<<32 * 512, 256, 0, stream>>>(x, dw_w, dw_b, xp);
    // 2-3. LN1 stats + apply/transpose -> a_ln
    ln1_stats_k<<<128, 256, 0, stream>>>(xp, mean1, rstd1);
    ln1_apply_k<<<1024, 256, 0, stream>>>(xp, mean1, rstd1, ln1_g, ln1_b, a_ln);
    // 4. QKV gemm -> qkvp (permuted)
    {
        GP p{}; p.A = a_ln; p.W = wq; p.bias = qkv_b; p.outB = qkvp; p.K = 512;
        mgemm_k<0, 128><<<dim3(12, 64), 256, 0, stream>>>(p);
    }
    // 5. attention
    attn_k<<<256, 256, 0, stream>>>(qkvp, mask_u, temp, attn_o);
    // 6. proj gemm (x2) -> t2
    {
        GP p{}; p.A = attn_o; p.W = wp; p.bias = proj_b; p.outB = t2; p.K = 512;
        mgemm_k<1, 128><<<dim3(4, 64), 256, 0, stream>>>(p);
    }
    // 7. convT gemm -> y0 (split yB/yT), channels-last
    {
        GP p{}; p.A = t2; p.W = wc; p.bias = ct_b;
        p.outB = yB; p.outB2 = yT; p.K = 512;
        mgemm_k<2, 128><<<dim3(16, 64), 256, 0, stream>>>(p);
    }
    // 8. LN2 fused stats+normalize in place
    ln2_fuse_k<<<8192, 256, 0, stream>>>(yB, yT, ln2_g, ln2_b);
    // 9. MLP in 4 chunks of 8192 rows
    for (int c = 0; c < 4; ++c) {
        int m0 = c * 8192;
        const ushort* yChunk = (c == 0) ? yB : (yT + (size_t)(m0 - 8192) * 512);
        {
            GP p{}; p.A = yChunk; p.W = w1; p.bias = pw1_b; p.outB = h1c; p.K = 512;
            mgemm_k<3, 128><<<dim3(16, 64), 256, 0, stream>>>(p);
        }
        {
            GP p{}; p.A = h1c; p.W = w2; p.bias = pw2_b;
            p.outF = (float*)d_out; p.inp = x; p.K = 2048; p.m0 = m0;
            mgemm_k<4, 64><<<dim3(8, 64), 256, 0, stream>>>(p);
        }
    }
}

// Round 3
// 671.540 us; speedup vs baseline: 1.0961x; 1.0646x over previous
//
#include <hip/hip_runtime.h>
#include <hip/hip_bf16.h>
#include <math.h>

typedef unsigned short ushort;
typedef __attribute__((ext_vector_type(8))) short short8;
typedef __attribute__((ext_vector_type(8))) unsigned short ushort8;
typedef __attribute__((ext_vector_type(4))) unsigned short ushort4v;
typedef __attribute__((ext_vector_type(4))) float f32x4;

__device__ __forceinline__ ushort f2bb(float v) {
    return __builtin_bit_cast(ushort, __float2bfloat16(v));
}
__device__ __forceinline__ float bf2f(ushort u) {
    return __bfloat162float(__builtin_bit_cast(__hip_bfloat16, u));
}
// async global->LDS 16B/lane; LDS dest = wave-uniform base + lane*16
__device__ __forceinline__ void gl2lds16(const ushort* g, ushort* l) {
    __builtin_amdgcn_global_load_lds(
        (const __attribute__((address_space(1))) unsigned int*)g,
        (__attribute__((address_space(3))) unsigned int*)l, 16, 0, 0);
}

// ---------------------------------------------------------------------------
// B=32, C=512, H=W=32, NH=8, dh=64, N=256 pooled, hidden=2048.
// r3: double-buffered K-loop (T3-minimum): issue next K-tile's global_load_lds
// BEFORE computing the current tile; single __syncthreads per K-step (its
// implicit vmcnt(0) drains loads that were in flight under the MFMA phase).
// r2 (kept): K-chunk XOR swizzle both sides (bank-conflict 3.1M -> 0),
// LDS-restaged full-line epilogue stores (WRITE = ideal), XCD-band swizzle
// (FETCH = ideal).
// ---------------------------------------------------------------------------

__global__ __launch_bounds__(256) void cvtw_k(const float* __restrict__ in,
                                              ushort* __restrict__ out, int n4) {
    int i = blockIdx.x * 256 + threadIdx.x;
    if (i >= n4) return;
    float4 v = ((const float4*)in)[i];
    ushort4v o;
    o.x = f2bb(v.x); o.y = f2bb(v.y); o.z = f2bb(v.z); o.w = f2bb(v.w);
    ((ushort4v*)out)[i] = o;
}

// ct_w [512][2048] fp32 -> [2048][512] bf16
__global__ __launch_bounds__(256) void cvtt_k(const float* __restrict__ in,
                                              ushort* __restrict__ out) {
    __shared__ float tl[32][33];
    int c0 = blockIdx.y * 32, j0 = blockIdx.x * 32;
    int tr = threadIdx.x >> 5, tc = threadIdx.x & 31;
#pragma unroll
    for (int p4 = 0; p4 < 4; ++p4)
        tl[tr + p4 * 8][tc] = in[(size_t)(c0 + tr + p4 * 8) * 2048 + j0 + tc];
    __syncthreads();
#pragma unroll
    for (int p4 = 0; p4 < 4; ++p4)
        out[(size_t)(j0 + tr + p4 * 8) * 512 + c0 + tc] = f2bb(tl[tc][tr + p4 * 8]);
}

// K1: depthwise 3x3 + bias + residual + 2x2 avgpool -> xp bf16 [B,C,16,16]
__global__ __launch_bounds__(256) void dwpool_k(const float* __restrict__ x,
                                                const float* __restrict__ dww,
                                                const float* __restrict__ dwb,
                                                ushort* __restrict__ xp) {
    int bc = blockIdx.x;
    int c = bc & 511;
    __shared__ float tile[32][33];
    __shared__ float w9[9];
    const float* xb = x + (size_t)bc * 1024;
    int tid = threadIdx.x;
    for (int i = tid; i < 1024; i += 256) tile[i >> 5][i & 31] = xb[i];
    if (tid < 9) w9[tid] = dww[c * 9 + tid];
    __syncthreads();
    float bv = dwb[c];
    int ph = tid >> 4, pw = tid & 15;
    float s = 0.f;
#pragma unroll
    for (int dy = 0; dy < 2; ++dy) {
#pragma unroll
        for (int dx = 0; dx < 2; ++dx) {
            int hh = 2 * ph + dy, ww = 2 * pw + dx;
            float a = bv + tile[hh][ww];
#pragma unroll
            for (int ky = 0; ky < 3; ++ky) {
                int yy = hh + ky - 1;
                if (yy < 0 || yy > 31) continue;
#pragma unroll
                for (int kx = 0; kx < 3; ++kx) {
                    int xx = ww + kx - 1;
                    if (xx < 0 || xx > 31) continue;
                    a += w9[ky * 3 + kx] * tile[yy][xx];
                }
            }
            s += a;
        }
    }
    xp[(size_t)bc * 256 + tid] = f2bb(0.25f * s);
}

// K2: LN1 stats per token over C=512; xp bf16 [b][c][n]
__global__ __launch_bounds__(256) void ln1_stats_k(const ushort* __restrict__ xp,
                                                   float* __restrict__ m1,
                                                   float* __restrict__ r1) {
    __shared__ float sh_s[4][64], sh_q[4][64];
    int blk = blockIdx.x;
    int b = blk >> 2;
    int n0 = (blk & 3) * 64;
    int t = threadIdx.x & 63, w = threadIdx.x >> 6;
    float s = 0.f, ss = 0.f;
    for (int i = 0; i < 128; ++i) {
        int c = w * 128 + i;
        float v = bf2f(xp[(size_t)(b * 512 + c) * 256 + n0 + t]);
        s += v; ss += v * v;
    }
    sh_s[w][t] = s; sh_q[w][t] = ss;
    __syncthreads();
    if (w == 0) {
        s  = sh_s[0][t] + sh_s[1][t] + sh_s[2][t] + sh_s[3][t];
        ss = sh_q[0][t] + sh_q[1][t] + sh_q[2][t] + sh_q[3][t];
        float m = s * (1.0f / 512.0f);
        m1[b * 256 + n0 + t] = m;
        r1[b * 256 + n0 + t] = rsqrtf(ss * (1.0f / 512.0f) - m * m + 1e-6f);
    }
}

// K3: LN1 apply + transpose: xp [b][c][n] -> a_ln [m][c] bf16 normalized
__global__ __launch_bounds__(256) void ln1_apply_k(const ushort* __restrict__ xp,
                                                   const float* __restrict__ m1,
                                                   const float* __restrict__ r1,
                                                   const float* __restrict__ g,
                                                   const float* __restrict__ beta,
                                                   ushort* __restrict__ a_ln) {
    __shared__ float tl[64][66];
    int blk = blockIdx.x;                 // b*32 + ct*4 + nt
    int b = blk >> 5, ct = (blk >> 2) & 7, nt = blk & 3;
    int t = threadIdx.x;
    int rq = t >> 6, nl = t & 63;
#pragma unroll
    for (int i = 0; i < 16; ++i) {
        int r = rq * 16 + i;
        int c = ct * 64 + r;
        tl[r][nl] = bf2f(xp[(size_t)(b * 512 + c) * 256 + nt * 64 + nl]);
    }
    __syncthreads();
    int r2 = t >> 2, cq = t & 3;
    int m = b * 256 + nt * 64 + r2;
    float mu = m1[m], rs = r1[m];
#pragma unroll
    for (int hh = 0; hh < 2; ++hh) {
        ushort8 o;
#pragma unroll
        for (int j = 0; j < 8; ++j) {
            int cl = cq * 16 + hh * 8 + j;
            int c = ct * 64 + cl;
            o[j] = f2bb((tl[cl][r2] - mu) * rs * g[c] + beta[c]);
        }
        *(ushort8*)&a_ln[(size_t)m * 512 + ct * 64 + cq * 16 + hh * 8] = o;
    }
}

// K7: LN2 fused stats+normalize, in place. y0 rows split across yB / yT.
__global__ __launch_bounds__(256) void ln2_fuse_k(ushort* __restrict__ yB,
                                                  ushort* __restrict__ yT,
                                                  const float* __restrict__ g,
                                                  const float* __restrict__ beta) {
    int w = threadIdx.x >> 6, lane = threadIdx.x & 63;
    int row = blockIdx.x * 4 + w;
    ushort* base = (row < 8192) ? (yB + (size_t)row * 512)
                                : (yT + (size_t)(row - 8192) * 512);
    ushort8 raw = *(ushort8*)&base[lane * 8];
    float v[8];
    float s = 0.f, ss = 0.f;
#pragma unroll
    for (int j = 0; j < 8; ++j) { v[j] = bf2f(raw[j]); s += v[j]; ss += v[j] * v[j]; }
#pragma unroll
    for (int off = 1; off < 64; off <<= 1) { s += __shfl_xor(s, off); ss += __shfl_xor(ss, off); }
    float mu = s * (1.0f / 512.0f);
    float rs = rsqrtf(ss * (1.0f / 512.0f) - mu * mu + 1e-6f);
    ushort8 o;
#pragma unroll
    for (int j = 0; j < 8; ++j) {
        int c = lane * 8 + j;
        o[j] = f2bb((v[j] - mu) * rs * g[c] + beta[c]);
    }
    *(ushort8*)&base[lane * 8] = o;
}

// ---------------------------------------------------------------------------
// MFMA GEMM: out[m,j] = sum_k A[m,k]*W[j,k]; A,W bf16 row-major.
// 128xBN tile, BK=32, 256 thr, double-buffered LDS with prefetch-ahead.
// MODE 0 QKV : out bf16 permuted q/k/v [3][256][64][256] (n-fast)
// MODE 1 PROJ: out bf16 t2 = 2*(acc+bias), row-major LD=512
// MODE 2 CONVT: bf16 channels-last y0 (split base) + ct_b, 64B/pixel chunks
// MODE 3 PW1 : out bf16 gelu(acc+bias), row-major LD=2048
// MODE 4 PW2 : out fp32 d_out = inp + acc + bias (hw-fast, float4 ld/st)
// ---------------------------------------------------------------------------
struct GP {
    const ushort* A;
    const ushort* W;
    const float* bias;
    ushort* outB;
    ushort* outB2;
    float* outF;
    const float* inp;
    int K, m0;
};

template <int MODE, int BN>
__global__ __launch_bounds__(256) void mgemm_k(GP p) {
    constexpr int MT = (BN == 128) ? 4 : 2;   // 16-row m-tiles per wave
    constexpr int NT = 4;                     // 16-col n-tiles per wave
    constexpr int ATILE = 128 * 32;           // ushorts per A K-tile
    constexpr int BTILE = BN * 32;            // ushorts per B K-tile
    constexpr int SMEM_US = 2 * (ATILE + BTILE);  // dbuf; >= all epilogue needs
    __shared__ __align__(16) ushort smem[SMEM_US];
    int tid = threadIdx.x;
    int lane = tid & 63, w = tid >> 6;
    int lr = lane & 15, lq = lane >> 4;
    int mwoff = (BN == 128) ? (w >> 1) * 64 : w * 32;
    int nwoff = (BN == 128) ? (w & 1) * 64 : 0;
    // ---- XCD-band swizzle (bijective: nwg % 8 == 0 for all grids) ----
    int gx = gridDim.x;
    int wgid = blockIdx.y * gx + blockIdx.x;
    int cpx = (gx * gridDim.y) >> 3;          // blocks per XCD
    int swz = (wgid & 7) * cpx + (wgid >> 3);
    int bx = swz % gx, by = swz / gx;
    int mbase = by * 128, nbase = bx * BN;
    // staging: 16 rows x 4 chunks; source chunk permuted so linear LDS dest
    // holds the swizzled layout (rule #21)
    int lsub = lane >> 2;
    int cchunk = (lane & 3) ^ ((lsub >> 1) & 3);
    int lcol = cchunk * 8;
    int physc = lq ^ ((lr >> 1) & 3);         // frag-read phys chunk
    f32x4 acc[MT][NT] = {};

    auto stage = [&](int buf, int kb) {
        ushort* Ab = smem + buf * ATILE;
        ushort* Bb = smem + 2 * ATILE + buf * BTILE;
#pragma unroll
        for (int i = 0; i < 2; ++i) {
            int row = w * 32 + i * 16;
            gl2lds16(p.A + (size_t)(mbase + row + lsub) * p.K + kb + lcol,
                     &Ab[row * 32]);
        }
        if constexpr (BN == 128) {
#pragma unroll
            for (int i = 0; i < 2; ++i) {
                int row = w * 32 + i * 16;
                gl2lds16(p.W + (size_t)(nbase + row + lsub) * p.K + kb + lcol,
                         &Bb[row * 32]);
            }
        } else {
            int row = w * 16;
            gl2lds16(p.W + (size_t)(nbase + row + lsub) * p.K + kb + lcol,
                     &Bb[row * 32]);
        }
    };

    // prologue: stage tile 0, wait (implicit vmcnt(0) in syncthreads)
    stage(0, 0);
    __syncthreads();
    int nk = p.K >> 5;
    for (int t = 0; t < nk; ++t) {
        int cur = t & 1;
        if (t + 1 < nk) stage(cur ^ 1, (t + 1) << 5);   // prefetch next tile
        const ushort* Ac = smem + cur * ATILE;
        const ushort* Bc = smem + 2 * ATILE + cur * BTILE;
        short8 af[MT], bfr[NT];
#pragma unroll
        for (int tt = 0; tt < MT; ++tt)
            af[tt] = *(const short8*)&Ac[(mwoff + tt * 16 + lr) * 32 + physc * 8];
#pragma unroll
        for (int tt = 0; tt < NT; ++tt)
            bfr[tt] = *(const short8*)&Bc[(nwoff + tt * 16 + lr) * 32 + physc * 8];
#pragma unroll
        for (int i = 0; i < MT; ++i)
#pragma unroll
            for (int j = 0; j < NT; ++j)
                acc[i][j] = __builtin_amdgcn_mfma_f32_16x16x32_bf16(af[i], bfr[j], acc[i][j], 0, 0, 0);
        __syncthreads();   // drains vmcnt(0): next buffer ready for all waves
    }

    // ================= epilogues (LDS restage -> vector stores) =============
    if constexpr (MODE == 1 || MODE == 3) {
        // row-major bf16 out, cols fast. eb [128][64] us, chunk^(row&7) swizzle.
        const size_t LD = (MODE == 1) ? 512 : 2048;
        ushort* eb = (ushort*)smem;
#pragma unroll
        for (int h = 0; h < 2; ++h) {
            __syncthreads();
            if ((w & 1) == h) {
#pragma unroll
                for (int ti = 0; ti < MT; ++ti)
#pragma unroll
                    for (int tj = 0; tj < NT; ++tj)
#pragma unroll
                        for (int r = 0; r < 4; ++r) {
                            int row = mwoff + ti * 16 + lq * 4 + r;     // 0..127
                            int colh = tj * 16 + lr;                    // 0..63
                            float v = acc[ti][tj][r] + p.bias[nbase + h * 64 + colh];
                            if constexpr (MODE == 1) v *= 2.0f;
                            else v = 0.5f * v * (1.0f + erff(v * 0.70710678118654752f));
                            int ph = (colh >> 3) ^ (row & 7);
                            eb[row * 64 + ph * 8 + (colh & 7)] = f2bb(v);
                        }
            }
            __syncthreads();
#pragma unroll
            for (int i = 0; i < 4; ++i) {
                int row = i * 32 + (tid >> 3);
                int ch = tid & 7;
                int pch = ch ^ (row & 7);
                short8 d = *(short8*)&eb[row * 64 + pch * 8];
                *(short8*)&p.outB[(size_t)(mbase + row) * LD + nbase + h * 64 + ch * 8] = d;
            }
        }
    } else if constexpr (MODE == 0) {
        // QKV permuted out, n-fast. eb [32 c][136 row-us].
        ushort* eb = (ushort*)smem;
        int b = mbase >> 8, n0 = mbase & 255;
#pragma unroll
        for (int pc = 0; pc < 4; ++pc) {
            __syncthreads();
            if ((w & 1) == (pc >> 1)) {
                int tjb = (pc & 1) * 2;
#pragma unroll
                for (int ti = 0; ti < MT; ++ti)
#pragma unroll
                    for (int tj2 = 0; tj2 < 2; ++tj2)
#pragma unroll
                        for (int r = 0; r < 4; ++r) {
                            int tj = tjb + tj2;
                            int row = mwoff + ti * 16 + lq * 4 + r;
                            int cl = tj2 * 16 + lr;                    // 0..31
                            float v = acc[ti][tj][r] + p.bias[nbase + pc * 32 + cl];
                            eb[cl * 136 + row] = f2bb(v);
                        }
            }
            __syncthreads();
#pragma unroll
            for (int i = 0; i < 2; ++i) {
                int dl = (tid >> 4) + 16 * i;                          // 0..31
                int ch = tid & 15;                                     // 8-n chunk
                short8 d = *(short8*)&eb[dl * 136 + ch * 8];
                int cg = nbase + pc * 32 + dl;
                int sect = cg >> 9, hh = (cg >> 6) & 7, dd = cg & 63;
                size_t addr = ((size_t)(sect * 256 + b * 8 + hh) * 64 + dd) * 256 + n0 + ch * 8;
                *(short8*)&p.outB[addr] = d;
            }
        }
    } else if constexpr (MODE == 2) {
        // convT pixel scatter -> eb [256 pix][40 us], 64B/pixel stores.
        ushort* eb = (ushort*)smem;
        ushort* ybase = (mbase < 2048) ? p.outB : (p.outB2 - (size_t)8192 * 512);
        int obase = nbase >> 2;
#pragma unroll
        for (int hf = 0; hf < 2; ++hf) {
            __syncthreads();
            if ((w >> 1) == hf) {
#pragma unroll
                for (int ti = 0; ti < MT; ++ti)
#pragma unroll
                    for (int tj = 0; tj < NT; ++tj)
#pragma unroll
                        for (int r = 0; r < 4; ++r) {
                            int rl = (mwoff - hf * 64) + ti * 16 + lq * 4 + r; // 0..63
                            int cgl = nwoff + tj * 16 + lr;                    // 0..127
                            int o_l = cgl >> 2, pp = (cgl >> 1) & 1, qq = cgl & 1;
                            int pix = ((rl >> 4) * 2 + pp) * 32 + (rl & 15) * 2 + qq;
                            float v = acc[ti][tj][r] + p.bias[obase + o_l];
                            eb[pix * 40 + o_l] = f2bb(v);
                        }
            }
            __syncthreads();
            int hhbase = ((mbase & 255) >> 4) + hf * 4;
            int prb = (mbase >> 8) * 32 + 2 * hhbase;
#pragma unroll
            for (int i = 0; i < 4; ++i) {
                int pix = i * 64 + (tid >> 2);
                int ch = tid & 3;
                short8 d = *(short8*)&eb[pix * 40 + ch * 8];
                int pr = (prb + (pix >> 5)) * 32 + (pix & 31);
                *(short8*)&ybase[(size_t)pr * 512 + obase + ch * 8] = d;
            }
        }
    } else {
        // MODE 4: fp32 out, hw(=row)-fast. ef [32 c][132 row-f32], float4 I/O.
        float* ef = (float*)smem;
        int gm0 = p.m0 + mbase;
        int b = gm0 >> 10, hw0 = gm0 & 1023;
#pragma unroll
        for (int pc = 0; pc < 2; ++pc) {
            __syncthreads();
#pragma unroll
            for (int ti = 0; ti < MT; ++ti)
#pragma unroll
                for (int tj2 = 0; tj2 < 2; ++tj2)
#pragma unroll
                    for (int r = 0; r < 4; ++r) {
                        int tj = pc * 2 + tj2;
                        int row = mwoff + ti * 16 + lq * 4 + r;        // 0..127
                        int cl = tj2 * 16 + lr;                        // 0..31
                        ef[cl * 132 + row] = acc[ti][tj][r] + p.bias[nbase + pc * 32 + cl];
                    }
            __syncthreads();
#pragma unroll
            for (int i = 0; i < 4; ++i) {
                int cl = (tid >> 5) + 8 * i;                           // 0..31
                int ck = tid & 31;                                     // 4-row chunk
                float4 v4 = *(float4*)&ef[cl * 132 + ck * 4];
                int c = nbase + pc * 32 + cl;
                size_t idx = ((size_t)(b * 512 + c)) * 1024 + hw0 + ck * 4;
                float4 xin = *(const float4*)&p.inp[idx];
                float4 o4;
                o4.x = xin.x + v4.x; o4.y = xin.y + v4.y;
                o4.z = xin.z + v4.z; o4.w = xin.w + v4.w;
                *(float4*)&p.outF[idx] = o4;
            }
        }
    }
}

// ---------------------------------------------------------------------------
// K5: cosine attention per (b,h). qkvp bf16 [3][256][64][256].
// ---------------------------------------------------------------------------
__global__ __launch_bounds__(256) void attn_k(const ushort* __restrict__ qkvp,
                                              const float* __restrict__ mask_u,
                                              const float* __restrict__ temp,
                                              ushort* __restrict__ attn_out) {
    __shared__ float bufA[64 * 65];
    __shared__ float bufB[64 * 65];
    __shared__ float Sb[64 * 65];
    __shared__ float fq[64], fk[64];
    int tid = threadIdx.x;
    int bh = blockIdx.x;
    int b = bh >> 3, h = bh & 7;
    const ushort* q = qkvp + (size_t)bh * 16384;
    const ushort* k = qkvp + 4194304 + (size_t)bh * 16384;
    const ushort* v = qkvp + 8388608 + (size_t)bh * 16384;
    int wv = tid >> 6, lane = tid & 63;

    for (int rr = 0; rr < 16; ++rr) {
        int row = wv * 16 + rr;
        float s = 0.f;
#pragma unroll
        for (int i = 0; i < 4; ++i) { float xv = bf2f(q[row * 256 + lane + i * 64]); s += xv * xv; }
#pragma unroll
        for (int off = 32; off; off >>= 1) s += __shfl_down(s, off);
        if (lane == 0) fq[row] = 1.0f / fmaxf(sqrtf(s), 1e-12f);
        s = 0.f;
#pragma unroll
        for (int i = 0; i < 4; ++i) { float xv = bf2f(k[row * 256 + lane + i * 64]); s += xv * xv; }
#pragma unroll
        for (int off = 32; off; off >>= 1) s += __shfl_down(s, off);
        if (lane == 0) fk[row] = 1.0f / fmaxf(sqrtf(s), 1e-12f);
    }
    __syncthreads();

    int tx = tid & 15, ty = tid >> 4;
    float acc[4][4] = {};
    for (int nb = 0; nb < 256; nb += 64) {
        __syncthreads();
#pragma unroll
        for (int it = 0; it < 16; ++it) {
            int f = it * 256 + tid;
            int d = f >> 6, n = f & 63;
            bufA[d * 65 + n] = bf2f(q[d * 256 + nb + n]);
            bufB[d * 65 + n] = bf2f(k[d * 256 + nb + n]);
        }
        __syncthreads();
#pragma unroll 8
        for (int kk = 0; kk < 64; ++kk) {
            float a[4], bb[4];
#pragma unroll
            for (int i = 0; i < 4; ++i) a[i] = bufA[(ty * 4 + i) * 65 + kk];
#pragma unroll
            for (int j = 0; j < 4; ++j) bb[j] = bufB[(tx * 4 + j) * 65 + kk];
#pragma unroll
            for (int i = 0; i < 4; ++i)
#pragma unroll
                for (int j = 0; j < 4; ++j) acc[i][j] += a[i] * bb[j];
        }
    }
    float tv = temp[h];
    __syncthreads();
#pragma unroll
    for (int i = 0; i < 4; ++i) {
        int d = ty * 4 + i;
#pragma unroll
        for (int j = 0; j < 4; ++j) {
            int e = tx * 4 + j;
            float sc = acc[i][j] * fq[d] * fk[e] * tv;
            float mu = mask_u[((size_t)bh * 64 + d) * 64 + e];
            if (mu < 0.2f) sc -= 1e12f;
            Sb[d * 65 + e] = sc;
        }
    }
    __syncthreads();

    {
        int row = tid >> 2, sub = tid & 3;
        float ev[16];
        float mx = -INFINITY;
#pragma unroll
        for (int i = 0; i < 16; ++i) { float s = Sb[row * 65 + sub * 16 + i]; ev[i] = s; mx = fmaxf(mx, s); }
        mx = fmaxf(mx, __shfl_xor(mx, 1));
        mx = fmaxf(mx, __shfl_xor(mx, 2));
        float sum = 0.f;
#pragma unroll
        for (int i = 0; i < 16; ++i) { ev[i] = expf(ev[i] - mx); sum += ev[i]; }
        sum += __shfl_xor(sum, 1);
        sum += __shfl_xor(sum, 2);
        float inv = 1.0f / sum;
#pragma unroll
        for (int i = 0; i < 16; ++i) Sb[row * 65 + sub * 16 + i] = ev[i] * inv;
    }
    __syncthreads();

    for (int nb = 0; nb < 256; nb += 64) {
        __syncthreads();
#pragma unroll
        for (int it = 0; it < 16; ++it) {
            int f = it * 256 + tid;
            int e = f >> 6, n = f & 63;
            bufA[e * 65 + n] = bf2f(v[e * 256 + nb + n]);
        }
        __syncthreads();
        float o[4][4] = {};
#pragma unroll 8
        for (int kk = 0; kk < 64; ++kk) {
            float a[4], bb[4];
#pragma unroll
            for (int i = 0; i < 4; ++i) a[i] = Sb[(ty * 4 + i) * 65 + kk];
#pragma unroll
            for (int j = 0; j < 4; ++j) bb[j] = bufA[kk * 65 + tx * 4 + j];
#pragma unroll
            for (int i = 0; i < 4; ++i)
#pragma unroll
                for (int j = 0; j < 4; ++j) o[i][j] += a[i] * bb[j];
        }
#pragma unroll
        for (int j = 0; j < 4; ++j) {
            int n = nb + tx * 4 + j;
            size_t base = ((size_t)(b * 256 + n)) * 512 + h * 64 + ty * 4;
#pragma unroll
            for (int i = 0; i < 4; ++i) attn_out[base + i] = f2bb(o[i][j]);
        }
    }
}

// ---------------------------------------------------------------------------
extern "C" void kernel_launch(void* const* d_in, const int* in_sizes, int n_in,
                              void* d_out, int out_size, void* d_ws, size_t ws_size,
                              hipStream_t stream) {
    const float* x      = (const float*)d_in[0];
    const float* mask_u = (const float*)d_in[1];
    const float* dw_w   = (const float*)d_in[2];
    const float* dw_b   = (const float*)d_in[3];
    const float* ln1_g  = (const float*)d_in[4];
    const float* ln1_b  = (const float*)d_in[5];
    const float* qkv_w  = (const float*)d_in[6];
    const float* qkv_b  = (const float*)d_in[7];
    const float* temp   = (const float*)d_in[8];
    const float* proj_w = (const float*)d_in[9];
    const float* proj_b = (const float*)d_in[10];
    const float* ct_w   = (const float*)d_in[11];
    const float* ct_b   = (const float*)d_in[12];
    const float* ln2_g  = (const float*)d_in[13];
    const float* ln2_b  = (const float*)d_in[14];
    const float* pw1_w  = (const float*)d_in[15];
    const float* pw1_b  = (const float*)d_in[16];
    const float* pw2_w  = (const float*)d_in[17];
    const float* pw2_b  = (const float*)d_in[18];

    char* wsb = (char*)d_ws;
    float* mean1 = (float*)wsb;
    float* rstd1 = mean1 + 8192;
    ushort* wq = (ushort*)(wsb + 524288);
    ushort* wp = wq + 786432;
    ushort* wc = wp + 262144;
    ushort* w1 = wc + 1048576;
    ushort* w2 = w1 + 1048576;
    ushort* xp     = (ushort*)(wsb + 8912896);   // region A: 8 MiB
    ushort* t2     = xp;                         // A reuse
    ushort* a_ln   = (ushort*)(wsb + 17301504);  // region Br: 8 MiB
    ushort* yB     = a_ln;                       // Br reuse: y0 rows 0..8191
    ushort* qkvp   = (ushort*)(wsb + 25690112);  // region CD: 24 MiB
    ushort* attn_o = (ushort*)(wsb + 50855936);  // CD tail: 8 MiB
    ushort* h1c    = qkvp;                       // CD reuse: [8192][2048] 32 MiB
    ushort* yT     = (ushort*)(wsb + 59244544);  // region T: 24 MiB

    // 0. weight conversions
    cvtw_k<<<768,  256, 0, stream>>>(qkv_w,  wq, 196608);
    cvtw_k<<<256,  256, 0, stream>>>(proj_w, wp, 65536);
    cvtw_k<<<1024, 256, 0, stream>>>(pw1_w,  w1, 262144);
    cvtw_k<<<1024, 256, 0, stream>>>(pw2_w,  w2, 262144);
    cvtt_k<<<dim3(64, 16), 256, 0, stream>>>(ct_w, wc);
    // 1. depthwise conv + residual + avgpool
    dwpool_k<<<32 * 512, 256, 0, stream>>>(x, dw_w, dw_b, xp);
    // 2-3. LN1 stats + apply/transpose -> a_ln
    ln1_stats_k<<<128, 256, 0, stream>>>(xp, mean1, rstd1);
    ln1_apply_k<<<1024, 256, 0, stream>>>(xp, mean1, rstd1, ln1_g, ln1_b, a_ln);
    // 4. QKV gemm -> qkvp (permuted)
    {
        GP p{}; p.A = a_ln; p.W = wq; p.bias = qkv_b; p.outB = qkvp; p.K = 512;
        mgemm_k<0, 128><<<dim3(12, 64), 256, 0, stream>>>(p);
    }
    // 5. attention
    attn_k<<<256, 256, 0, stream>>>(qkvp, mask_u, temp, attn_o);
    // 6. proj gemm (x2) -> t2
    {
        GP p{}; p.A = attn_o; p.W = wp; p.bias = proj_b; p.outB = t2; p.K = 512;
        mgemm_k<1, 128><<<dim3(4, 64), 256, 0, stream>>>(p);
    }
    // 7. convT gemm -> y0 (split yB/yT), channels-last
    {
        GP p{}; p.A = t2; p.W = wc; p.bias = ct_b;
        p.outB = yB; p.outB2 = yT; p.K = 512;
        mgemm_k<2, 128><<<dim3(16, 64), 256, 0, stream>>>(p);
    }
    // 8. LN2 fused stats+normalize in place
    ln2_fuse_k<<<8192, 256, 0, stream>>>(yB, yT, ln2_g, ln2_b);
    // 9. MLP in 4 chunks of 8192 rows
    for (int c = 0; c < 4; ++c) {
        int m0 = c * 8192;
        const ushort* yChunk = (c == 0) ? yB : (yT + (size_t)(m0 - 8192) * 512);
        {
            GP p{}; p.A = yChunk; p.W = w1; p.bias = pw1_b; p.outB = h1c; p.K = 512;
            mgemm_k<3, 128><<<dim3(16, 64), 256, 0, stream>>>(p);
        }
        {
            GP p{}; p.A = h1c; p.W = w2; p.bias = pw2_b;
            p.outF = (float*)d_out; p.inp = x; p.K = 2048; p.m0 = m0;
            mgemm_k<4, 64><<<dim3(8, 64), 256, 0, stream>>>(p);
        }
    }
}

// Round 4
// 619.116 us; speedup vs baseline: 1.1890x; 1.0847x over previous
//
#include <hip/hip_runtime.h>
#include <hip/hip_bf16.h>
#include <math.h>

typedef unsigned short ushort;
typedef __attribute__((ext_vector_type(8))) short short8;
typedef __attribute__((ext_vector_type(8))) unsigned short ushort8;
typedef __attribute__((ext_vector_type(4))) unsigned short ushort4v;
typedef __attribute__((ext_vector_type(4))) float f32x4;

__device__ __forceinline__ ushort f2bb(float v) {
    return __builtin_bit_cast(ushort, __float2bfloat16(v));
}
__device__ __forceinline__ float bf2f(ushort u) {
    return __bfloat162float(__builtin_bit_cast(__hip_bfloat16, u));
}
// async global->LDS 16B/lane; LDS dest = wave-uniform base + lane*16
__device__ __forceinline__ void gl2lds16(const ushort* g, ushort* l) {
    __builtin_amdgcn_global_load_lds(
        (const __attribute__((address_space(1))) unsigned int*)g,
        (__attribute__((address_space(3))) unsigned int*)l, 16, 0, 0);
}

// ---------------------------------------------------------------------------
// B=32, C=512, H=W=32, NH=8, dh=64, N=256 pooled, hidden=2048.
// r4: attn_k rewritten on MFMA (was scalar VALU, MfmaUtil=0, 60us/dispatch):
//   QK^T and PV as 16x16x32 bf16 MFMA; frags loaded straight from global
//   (qkvp layout == frag layout); P packed bf16 into XOR-swizzled LDS; V
//   stored TRANSPOSED [bh][n][d] by the QKV-GEMM epilogue so PV's B-operand
//   is row-major-in-contraction. Softmax unchanged.
// r3 (kept): double-buffered GEMM K-loop (prefetch-ahead, 1 barrier/K-step).
// r2 (kept): K-chunk XOR swizzle (bank conflicts 0), full-line epilogue
// stores (WRITE ideal), XCD-band swizzle (FETCH ideal).
// ---------------------------------------------------------------------------

__global__ __launch_bounds__(256) void cvtw_k(const float* __restrict__ in,
                                              ushort* __restrict__ out, int n4) {
    int i = blockIdx.x * 256 + threadIdx.x;
    if (i >= n4) return;
    float4 v = ((const float4*)in)[i];
    ushort4v o;
    o.x = f2bb(v.x); o.y = f2bb(v.y); o.z = f2bb(v.z); o.w = f2bb(v.w);
    ((ushort4v*)out)[i] = o;
}

// ct_w [512][2048] fp32 -> [2048][512] bf16
__global__ __launch_bounds__(256) void cvtt_k(const float* __restrict__ in,
                                              ushort* __restrict__ out) {
    __shared__ float tl[32][33];
    int c0 = blockIdx.y * 32, j0 = blockIdx.x * 32;
    int tr = threadIdx.x >> 5, tc = threadIdx.x & 31;
#pragma unroll
    for (int p4 = 0; p4 < 4; ++p4)
        tl[tr + p4 * 8][tc] = in[(size_t)(c0 + tr + p4 * 8) * 2048 + j0 + tc];
    __syncthreads();
#pragma unroll
    for (int p4 = 0; p4 < 4; ++p4)
        out[(size_t)(j0 + tr + p4 * 8) * 512 + c0 + tc] = f2bb(tl[tc][tr + p4 * 8]);
}

// K1: depthwise 3x3 + bias + residual + 2x2 avgpool -> xp bf16 [B,C,16,16]
__global__ __launch_bounds__(256) void dwpool_k(const float* __restrict__ x,
                                                const float* __restrict__ dww,
                                                const float* __restrict__ dwb,
                                                ushort* __restrict__ xp) {
    int bc = blockIdx.x;
    int c = bc & 511;
    __shared__ float tile[32][33];
    __shared__ float w9[9];
    const float* xb = x + (size_t)bc * 1024;
    int tid = threadIdx.x;
    for (int i = tid; i < 1024; i += 256) tile[i >> 5][i & 31] = xb[i];
    if (tid < 9) w9[tid] = dww[c * 9 + tid];
    __syncthreads();
    float bv = dwb[c];
    int ph = tid >> 4, pw = tid & 15;
    float s = 0.f;
#pragma unroll
    for (int dy = 0; dy < 2; ++dy) {
#pragma unroll
        for (int dx = 0; dx < 2; ++dx) {
            int hh = 2 * ph + dy, ww = 2 * pw + dx;
            float a = bv + tile[hh][ww];
#pragma unroll
            for (int ky = 0; ky < 3; ++ky) {
                int yy = hh + ky - 1;
                if (yy < 0 || yy > 31) continue;
#pragma unroll
                for (int kx = 0; kx < 3; ++kx) {
                    int xx = ww + kx - 1;
                    if (xx < 0 || xx > 31) continue;
                    a += w9[ky * 3 + kx] * tile[yy][xx];
                }
            }
            s += a;
        }
    }
    xp[(size_t)bc * 256 + tid] = f2bb(0.25f * s);
}

// K2: LN1 stats per token over C=512; xp bf16 [b][c][n]
__global__ __launch_bounds__(256) void ln1_stats_k(const ushort* __restrict__ xp,
                                                   float* __restrict__ m1,
                                                   float* __restrict__ r1) {
    __shared__ float sh_s[4][64], sh_q[4][64];
    int blk = blockIdx.x;
    int b = blk >> 2;
    int n0 = (blk & 3) * 64;
    int t = threadIdx.x & 63, w = threadIdx.x >> 6;
    float s = 0.f, ss = 0.f;
    for (int i = 0; i < 128; ++i) {
        int c = w * 128 + i;
        float v = bf2f(xp[(size_t)(b * 512 + c) * 256 + n0 + t]);
        s += v; ss += v * v;
    }
    sh_s[w][t] = s; sh_q[w][t] = ss;
    __syncthreads();
    if (w == 0) {
        s  = sh_s[0][t] + sh_s[1][t] + sh_s[2][t] + sh_s[3][t];
        ss = sh_q[0][t] + sh_q[1][t] + sh_q[2][t] + sh_q[3][t];
        float m = s * (1.0f / 512.0f);
        m1[b * 256 + n0 + t] = m;
        r1[b * 256 + n0 + t] = rsqrtf(ss * (1.0f / 512.0f) - m * m + 1e-6f);
    }
}

// K3: LN1 apply + transpose: xp [b][c][n] -> a_ln [m][c] bf16 normalized
__global__ __launch_bounds__(256) void ln1_apply_k(const ushort* __restrict__ xp,
                                                   const float* __restrict__ m1,
                                                   const float* __restrict__ r1,
                                                   const float* __restrict__ g,
                                                   const float* __restrict__ beta,
                                                   ushort* __restrict__ a_ln) {
    __shared__ float tl[64][66];
    int blk = blockIdx.x;                 // b*32 + ct*4 + nt
    int b = blk >> 5, ct = (blk >> 2) & 7, nt = blk & 3;
    int t = threadIdx.x;
    int rq = t >> 6, nl = t & 63;
#pragma unroll
    for (int i = 0; i < 16; ++i) {
        int r = rq * 16 + i;
        int c = ct * 64 + r;
        tl[r][nl] = bf2f(xp[(size_t)(b * 512 + c) * 256 + nt * 64 + nl]);
    }
    __syncthreads();
    int r2 = t >> 2, cq = t & 3;
    int m = b * 256 + nt * 64 + r2;
    float mu = m1[m], rs = r1[m];
#pragma unroll
    for (int hh = 0; hh < 2; ++hh) {
        ushort8 o;
#pragma unroll
        for (int j = 0; j < 8; ++j) {
            int cl = cq * 16 + hh * 8 + j;
            int c = ct * 64 + cl;
            o[j] = f2bb((tl[cl][r2] - mu) * rs * g[c] + beta[c]);
        }
        *(ushort8*)&a_ln[(size_t)m * 512 + ct * 64 + cq * 16 + hh * 8] = o;
    }
}

// K7: LN2 fused stats+normalize, in place. y0 rows split across yB / yT.
__global__ __launch_bounds__(256) void ln2_fuse_k(ushort* __restrict__ yB,
                                                  ushort* __restrict__ yT,
                                                  const float* __restrict__ g,
                                                  const float* __restrict__ beta) {
    int w = threadIdx.x >> 6, lane = threadIdx.x & 63;
    int row = blockIdx.x * 4 + w;
    ushort* base = (row < 8192) ? (yB + (size_t)row * 512)
                                : (yT + (size_t)(row - 8192) * 512);
    ushort8 raw = *(ushort8*)&base[lane * 8];
    float v[8];
    float s = 0.f, ss = 0.f;
#pragma unroll
    for (int j = 0; j < 8; ++j) { v[j] = bf2f(raw[j]); s += v[j]; ss += v[j] * v[j]; }
#pragma unroll
    for (int off = 1; off < 64; off <<= 1) { s += __shfl_xor(s, off); ss += __shfl_xor(ss, off); }
    float mu = s * (1.0f / 512.0f);
    float rs = rsqrtf(ss * (1.0f / 512.0f) - mu * mu + 1e-6f);
    ushort8 o;
#pragma unroll
    for (int j = 0; j < 8; ++j) {
        int c = lane * 8 + j;
        o[j] = f2bb((v[j] - mu) * rs * g[c] + beta[c]);
    }
    *(ushort8*)&base[lane * 8] = o;
}

// ---------------------------------------------------------------------------
// MFMA GEMM: out[m,j] = sum_k A[m,k]*W[j,k]; A,W bf16 row-major.
// 128xBN tile, BK=32, 256 thr, double-buffered LDS with prefetch-ahead.
// MODE 0 QKV : out bf16 q/k [sect][bh][64 d][256 n]; V TRANSPOSED [bh][n][d]
// MODE 1 PROJ: out bf16 t2 = 2*(acc+bias), row-major LD=512
// MODE 2 CONVT: bf16 channels-last y0 (split base) + ct_b, 64B/pixel chunks
// MODE 3 PW1 : out bf16 gelu(acc+bias), row-major LD=2048
// MODE 4 PW2 : out fp32 d_out = inp + acc + bias (hw-fast, float4 ld/st)
// ---------------------------------------------------------------------------
struct GP {
    const ushort* A;
    const ushort* W;
    const float* bias;
    ushort* outB;
    ushort* outB2;
    float* outF;
    const float* inp;
    int K, m0;
};

template <int MODE, int BN>
__global__ __launch_bounds__(256) void mgemm_k(GP p) {
    constexpr int MT = (BN == 128) ? 4 : 2;   // 16-row m-tiles per wave
    constexpr int NT = 4;                     // 16-col n-tiles per wave
    constexpr int ATILE = 128 * 32;           // ushorts per A K-tile
    constexpr int BTILE = BN * 32;            // ushorts per B K-tile
    constexpr int SMEM_US = 2 * (ATILE + BTILE);  // dbuf; >= all epilogue needs
    __shared__ __align__(16) ushort smem[SMEM_US];
    int tid = threadIdx.x;
    int lane = tid & 63, w = tid >> 6;
    int lr = lane & 15, lq = lane >> 4;
    int mwoff = (BN == 128) ? (w >> 1) * 64 : w * 32;
    int nwoff = (BN == 128) ? (w & 1) * 64 : 0;
    // ---- XCD-band swizzle (bijective: nwg % 8 == 0 for all grids) ----
    int gx = gridDim.x;
    int wgid = blockIdx.y * gx + blockIdx.x;
    int cpx = (gx * gridDim.y) >> 3;          // blocks per XCD
    int swz = (wgid & 7) * cpx + (wgid >> 3);
    int bx = swz % gx, by = swz / gx;
    int mbase = by * 128, nbase = bx * BN;
    // staging: 16 rows x 4 chunks; source chunk permuted so linear LDS dest
    // holds the swizzled layout (rule #21)
    int lsub = lane >> 2;
    int cchunk = (lane & 3) ^ ((lsub >> 1) & 3);
    int lcol = cchunk * 8;
    int physc = lq ^ ((lr >> 1) & 3);         // frag-read phys chunk
    f32x4 acc[MT][NT] = {};

    auto stage = [&](int buf, int kb) {
        ushort* Ab = smem + buf * ATILE;
        ushort* Bb = smem + 2 * ATILE + buf * BTILE;
#pragma unroll
        for (int i = 0; i < 2; ++i) {
            int row = w * 32 + i * 16;
            gl2lds16(p.A + (size_t)(mbase + row + lsub) * p.K + kb + lcol,
                     &Ab[row * 32]);
        }
        if constexpr (BN == 128) {
#pragma unroll
            for (int i = 0; i < 2; ++i) {
                int row = w * 32 + i * 16;
                gl2lds16(p.W + (size_t)(nbase + row + lsub) * p.K + kb + lcol,
                         &Bb[row * 32]);
            }
        } else {
            int row = w * 16;
            gl2lds16(p.W + (size_t)(nbase + row + lsub) * p.K + kb + lcol,
                     &Bb[row * 32]);
        }
    };

    // prologue: stage tile 0, wait (implicit vmcnt(0) in syncthreads)
    stage(0, 0);
    __syncthreads();
    int nk = p.K >> 5;
    for (int t = 0; t < nk; ++t) {
        int cur = t & 1;
        if (t + 1 < nk) stage(cur ^ 1, (t + 1) << 5);   // prefetch next tile
        const ushort* Ac = smem + cur * ATILE;
        const ushort* Bc = smem + 2 * ATILE + cur * BTILE;
        short8 af[MT], bfr[NT];
#pragma unroll
        for (int tt = 0; tt < MT; ++tt)
            af[tt] = *(const short8*)&Ac[(mwoff + tt * 16 + lr) * 32 + physc * 8];
#pragma unroll
        for (int tt = 0; tt < NT; ++tt)
            bfr[tt] = *(const short8*)&Bc[(nwoff + tt * 16 + lr) * 32 + physc * 8];
#pragma unroll
        for (int i = 0; i < MT; ++i)
#pragma unroll
            for (int j = 0; j < NT; ++j)
                acc[i][j] = __builtin_amdgcn_mfma_f32_16x16x32_bf16(af[i], bfr[j], acc[i][j], 0, 0, 0);
        __syncthreads();   // drains vmcnt(0): next buffer ready for all waves
    }

    // ================= epilogues (LDS restage -> vector stores) =============
    if constexpr (MODE == 1 || MODE == 3) {
        // row-major bf16 out, cols fast. eb [128][64] us, chunk^(row&7) swizzle.
        const size_t LD = (MODE == 1) ? 512 : 2048;
        ushort* eb = (ushort*)smem;
#pragma unroll
        for (int h = 0; h < 2; ++h) {
            __syncthreads();
            if ((w & 1) == h) {
#pragma unroll
                for (int ti = 0; ti < MT; ++ti)
#pragma unroll
                    for (int tj = 0; tj < NT; ++tj)
#pragma unroll
                        for (int r = 0; r < 4; ++r) {
                            int row = mwoff + ti * 16 + lq * 4 + r;     // 0..127
                            int colh = tj * 16 + lr;                    // 0..63
                            float v = acc[ti][tj][r] + p.bias[nbase + h * 64 + colh];
                            if constexpr (MODE == 1) v *= 2.0f;
                            else v = 0.5f * v * (1.0f + erff(v * 0.70710678118654752f));
                            int ph = (colh >> 3) ^ (row & 7);
                            eb[row * 64 + ph * 8 + (colh & 7)] = f2bb(v);
                        }
            }
            __syncthreads();
#pragma unroll
            for (int i = 0; i < 4; ++i) {
                int row = i * 32 + (tid >> 3);
                int ch = tid & 7;
                int pch = ch ^ (row & 7);
                short8 d = *(short8*)&eb[row * 64 + pch * 8];
                *(short8*)&p.outB[(size_t)(mbase + row) * LD + nbase + h * 64 + ch * 8] = d;
            }
        }
    } else if constexpr (MODE == 0) {
        // QKV out. eb [32 c][136 row-us] per pc chunk.
        // Q/K (cg<1024): [sect][bh][d][n], n-fast stores.
        // V  (cg>=1024): TRANSPOSED [bh][n][d], d-fast stores.
        ushort* eb = (ushort*)smem;
        int b = mbase >> 8, n0 = mbase & 255;
#pragma unroll
        for (int pc = 0; pc < 4; ++pc) {
            __syncthreads();
            if ((w & 1) == (pc >> 1)) {
                int tjb = (pc & 1) * 2;
#pragma unroll
                for (int ti = 0; ti < MT; ++ti)
#pragma unroll
                    for (int tj2 = 0; tj2 < 2; ++tj2)
#pragma unroll
                        for (int r = 0; r < 4; ++r) {
                            int tj = tjb + tj2;
                            int row = mwoff + ti * 16 + lq * 4 + r;
                            int cl = tj2 * 16 + lr;                    // 0..31
                            float v = acc[ti][tj][r] + p.bias[nbase + pc * 32 + cl];
                            eb[cl * 136 + row] = f2bb(v);
                        }
            }
            __syncthreads();
            if (nbase < 1024) {
#pragma unroll
                for (int i = 0; i < 2; ++i) {
                    int dl = (tid >> 4) + 16 * i;                      // 0..31
                    int ch = tid & 15;                                 // 8-n chunk
                    short8 d = *(short8*)&eb[dl * 136 + ch * 8];
                    int cg = nbase + pc * 32 + dl;
                    int sect = cg >> 9, hh = (cg >> 6) & 7, dd = cg & 63;
                    size_t addr = ((size_t)(sect * 256 + b * 8 + hh) * 64 + dd) * 256 + n0 + ch * 8;
                    *(short8*)&p.outB[addr] = d;
                }
            } else {
                int cv = nbase + pc * 32 - 1024;   // V channel base (mult of 32)
                int bh2 = b * 8 + (cv >> 6);
                int d0 = cv & 63;                  // 0 or 32
#pragma unroll
                for (int i = 0; i < 2; ++i) {
                    int idx = i * 256 + tid;       // 0..511
                    int n = idx >> 2, oc = idx & 3;
                    ushort8 dv;
#pragma unroll
                    for (int j = 0; j < 8; ++j) dv[j] = eb[(oc * 8 + j) * 136 + n];
                    *(ushort8*)&p.outB[(size_t)8388608 + (size_t)bh2 * 16384 +
                                       (size_t)(n0 + n) * 64 + d0 + oc * 8] = dv;
                }
            }
        }
    } else if constexpr (MODE == 2) {
        // convT pixel scatter -> eb [256 pix][40 us], 64B/pixel stores.
        ushort* eb = (ushort*)smem;
        ushort* ybase = (mbase < 2048) ? p.outB : (p.outB2 - (size_t)8192 * 512);
        int obase = nbase >> 2;
#pragma unroll
        for (int hf = 0; hf < 2; ++hf) {
            __syncthreads();
            if ((w >> 1) == hf) {
#pragma unroll
                for (int ti = 0; ti < MT; ++ti)
#pragma unroll
                    for (int tj = 0; tj < NT; ++tj)
#pragma unroll
                        for (int r = 0; r < 4; ++r) {
                            int rl = (mwoff - hf * 64) + ti * 16 + lq * 4 + r; // 0..63
                            int cgl = nwoff + tj * 16 + lr;                    // 0..127
                            int o_l = cgl >> 2, pp = (cgl >> 1) & 1, qq = cgl & 1;
                            int pix = ((rl >> 4) * 2 + pp) * 32 + (rl & 15) * 2 + qq;
                            float v = acc[ti][tj][r] + p.bias[obase + o_l];
                            eb[pix * 40 + o_l] = f2bb(v);
                        }
            }
            __syncthreads();
            int hhbase = ((mbase & 255) >> 4) + hf * 4;
            int prb = (mbase >> 8) * 32 + 2 * hhbase;
#pragma unroll
            for (int i = 0; i < 4; ++i) {
                int pix = i * 64 + (tid >> 2);
                int ch = tid & 3;
                short8 d = *(short8*)&eb[pix * 40 + ch * 8];
                int pr = (prb + (pix >> 5)) * 32 + (pix & 31);
                *(short8*)&ybase[(size_t)pr * 512 + obase + ch * 8] = d;
            }
        }
    } else {
        // MODE 4: fp32 out, hw(=row)-fast. ef [32 c][132 row-f32], float4 I/O.
        float* ef = (float*)smem;
        int gm0 = p.m0 + mbase;
        int b = gm0 >> 10, hw0 = gm0 & 1023;
#pragma unroll
        for (int pc = 0; pc < 2; ++pc) {
            __syncthreads();
#pragma unroll
            for (int ti = 0; ti < MT; ++ti)
#pragma unroll
                for (int tj2 = 0; tj2 < 2; ++tj2)
#pragma unroll
                    for (int r = 0; r < 4; ++r) {
                        int tj = pc * 2 + tj2;
                        int row = mwoff + ti * 16 + lq * 4 + r;        // 0..127
                        int cl = tj2 * 16 + lr;                        // 0..31
                        ef[cl * 132 + row] = acc[ti][tj][r] + p.bias[nbase + pc * 32 + cl];
                    }
            __syncthreads();
#pragma unroll
            for (int i = 0; i < 4; ++i) {
                int cl = (tid >> 5) + 8 * i;                           // 0..31
                int ck = tid & 31;                                     // 4-row chunk
                float4 v4 = *(float4*)&ef[cl * 132 + ck * 4];
                int c = nbase + pc * 32 + cl;
                size_t idx = ((size_t)(b * 512 + c)) * 1024 + hw0 + ck * 4;
                float4 xin = *(const float4*)&p.inp[idx];
                float4 o4;
                o4.x = xin.x + v4.x; o4.y = xin.y + v4.y;
                o4.z = xin.z + v4.z; o4.w = xin.w + v4.w;
                *(float4*)&p.outF[idx] = o4;
            }
        }
    }
}

// ---------------------------------------------------------------------------
// K5: cosine attention per (b,h), MFMA. qkvp: Q,K [sect][bh][64 d][256 n];
// V transposed [bh][256 n][64 d]. Out attn_o [b*256+n][h*64+d] bf16.
// ---------------------------------------------------------------------------
__global__ __launch_bounds__(256) void attn_k(const ushort* __restrict__ qkvp,
                                              const float* __restrict__ mask_u,
                                              const float* __restrict__ temp,
                                              ushort* __restrict__ attn_out) {
    __shared__ float Sb[64 * 65];          // scores f32
    __shared__ ushort Pb[64 * 64];         // probs bf16, chunk^(row&7) swizzle
    __shared__ float fq[64], fk[64];
    int tid = threadIdx.x;
    int bh = blockIdx.x;
    int b = bh >> 3, h = bh & 7;
    const ushort* q  = qkvp + (size_t)bh * 16384;
    const ushort* k  = qkvp + 4194304 + (size_t)bh * 16384;
    const ushort* vt = qkvp + 8388608 + (size_t)bh * 16384;   // [256 n][64 d]
    int lane = tid & 63, w = tid >> 6;
    int lr = lane & 15, lq = lane >> 4;

    // ---- norms: 4 threads per row, 64 elems each ----
    {
        int row = tid >> 2, qd = tid & 3;
        const ushort* qr = q + row * 256 + qd * 64;
        const ushort* kr = k + row * 256 + qd * 64;
        float s = 0.f, t = 0.f;
#pragma unroll
        for (int i = 0; i < 8; ++i) {
            short8 a8 = *(const short8*)&qr[i * 8];
            short8 b8 = *(const short8*)&kr[i * 8];
#pragma unroll
            for (int j = 0; j < 8; ++j) {
                float fa = bf2f((ushort)a8[j]); s += fa * fa;
                float fb = bf2f((ushort)b8[j]); t += fb * fb;
            }
        }
        s += __shfl_xor(s, 1); s += __shfl_xor(s, 2);
        t += __shfl_xor(t, 1); t += __shfl_xor(t, 2);
        if (qd == 0) {
            fq[row] = 1.0f / fmaxf(sqrtf(s), 1e-12f);
            fk[row] = 1.0f / fmaxf(sqrtf(t), 1e-12f);
        }
    }
    __syncthreads();

    // ---- QK^T: 64x64, K=256. Wave quadrants 32x32 (2x2 tiles x 8 ksteps) ----
    int mq = (w >> 1) * 32, nq = (w & 1) * 32;
    f32x4 acc[2][2] = {};
    for (int kb = 0; kb < 256; kb += 32) {
        short8 af[2], bfr[2];
#pragma unroll
        for (int ti = 0; ti < 2; ++ti)
            af[ti] = *(const short8*)&q[(mq + ti * 16 + lr) * 256 + kb + lq * 8];
#pragma unroll
        for (int tj = 0; tj < 2; ++tj)
            bfr[tj] = *(const short8*)&k[(nq + tj * 16 + lr) * 256 + kb + lq * 8];
#pragma unroll
        for (int i = 0; i < 2; ++i)
#pragma unroll
            for (int j = 0; j < 2; ++j)
                acc[i][j] = __builtin_amdgcn_mfma_f32_16x16x32_bf16(af[i], bfr[j], acc[i][j], 0, 0, 0);
    }

    // ---- scale, mask, write S to LDS ----
    float tv = temp[h];
#pragma unroll
    for (int i = 0; i < 2; ++i)
#pragma unroll
        for (int r = 0; r < 4; ++r) {
            int d = mq + i * 16 + lq * 4 + r;
#pragma unroll
            for (int j = 0; j < 2; ++j) {
                int e = nq + j * 16 + lr;
                float sc = acc[i][j][r] * fq[d] * fk[e] * tv;
                float mu = mask_u[((size_t)bh * 64 + d) * 64 + e];
                if (mu < 0.2f) sc -= 1e12f;
                Sb[d * 65 + e] = sc;
            }
        }
    __syncthreads();

    // ---- softmax rows + pack P -> bf16 swizzled Pb ----
    {
        int row = tid >> 2, sub = tid & 3;
        float ev[16];
        float mx = -INFINITY;
#pragma unroll
        for (int i = 0; i < 16; ++i) { float s = Sb[row * 65 + sub * 16 + i]; ev[i] = s; mx = fmaxf(mx, s); }
        mx = fmaxf(mx, __shfl_xor(mx, 1));
        mx = fmaxf(mx, __shfl_xor(mx, 2));
        float sum = 0.f;
#pragma unroll
        for (int i = 0; i < 16; ++i) { ev[i] = expf(ev[i] - mx); sum += ev[i]; }
        sum += __shfl_xor(sum, 1);
        sum += __shfl_xor(sum, 2);
        float inv = 1.0f / sum;
        unsigned int* Pb32 = (unsigned int*)Pb;
#pragma unroll
        for (int kk = 0; kk < 8; ++kk) {
            unsigned int lo = f2bb(ev[2 * kk] * inv);
            unsigned int hi = f2bb(ev[2 * kk + 1] * inv);
            int c8 = sub * 2 + (kk >> 2);
            int ph = c8 ^ (row & 7);
            Pb32[row * 32 + ph * 4 + (kk & 3)] = (hi << 16) | lo;
        }
    }
    __syncthreads();

    // ---- PV: O[64 d][256 n] = P[64][64] * Vt[n][e]. Wave owns 64-n strip ----
    int nw = w * 64;
    f32x4 o[4][4] = {};
#pragma unroll
    for (int ks = 0; ks < 2; ++ks) {
        short8 pa[4];
#pragma unroll
        for (int mt = 0; mt < 4; ++mt) {
            int d = mt * 16 + lr;
            int ph = (ks * 4 + lq) ^ (d & 7);
            pa[mt] = *(const short8*)&Pb[d * 64 + ph * 8];
        }
#pragma unroll
        for (int nt = 0; nt < 4; ++nt) {
            short8 vb = *(const short8*)&vt[(size_t)(nw + nt * 16 + lr) * 64 + ks * 32 + lq * 8];
#pragma unroll
            for (int mt = 0; mt < 4; ++mt)
                o[mt][nt] = __builtin_amdgcn_mfma_f32_16x16x32_bf16(pa[mt], vb, o[mt][nt], 0, 0, 0);
        }
    }

    // ---- store O: attn_o[b*256+n][h*64+d], 8B packed per (mt,nt) ----
#pragma unroll
    for (int mt = 0; mt < 4; ++mt) {
        int d0 = mt * 16 + lq * 4;
#pragma unroll
        for (int nt = 0; nt < 4; ++nt) {
            int n = nw + nt * 16 + lr;
            ushort4v ov;
#pragma unroll
            for (int r = 0; r < 4; ++r) ov[r] = f2bb(o[mt][nt][r]);
            *(ushort4v*)&attn_out[((size_t)(b * 256 + n)) * 512 + h * 64 + d0] = ov;
        }
    }
}

// ---------------------------------------------------------------------------
extern "C" void kernel_launch(void* const* d_in, const int* in_sizes, int n_in,
                              void* d_out, int out_size, void* d_ws, size_t ws_size,
                              hipStream_t stream) {
    const float* x      = (const float*)d_in[0];
    const float* mask_u = (const float*)d_in[1];
    const float* dw_w   = (const float*)d_in[2];
    const float* dw_b   = (const float*)d_in[3];
    const float* ln1_g  = (const float*)d_in[4];
    const float* ln1_b  = (const float*)d_in[5];
    const float* qkv_w  = (const float*)d_in[6];
    const float* qkv_b  = (const float*)d_in[7];
    const float* temp   = (const float*)d_in[8];
    const float* proj_w = (const float*)d_in[9];
    const float* proj_b = (const float*)d_in[10];
    const float* ct_w   = (const float*)d_in[11];
    const float* ct_b   = (const float*)d_in[12];
    const float* ln2_g  = (const float*)d_in[13];
    const float* ln2_b  = (const float*)d_in[14];
    const float* pw1_w  = (const float*)d_in[15];
    const float* pw1_b  = (const float*)d_in[16];
    const float* pw2_w  = (const float*)d_in[17];
    const float* pw2_b  = (const float*)d_in[18];

    char* wsb = (char*)d_ws;
    float* mean1 = (float*)wsb;
    float* rstd1 = mean1 + 8192;
    ushort* wq = (ushort*)(wsb + 524288);
    ushort* wp = wq + 786432;
    ushort* wc = wp + 262144;
    ushort* w1 = wc + 1048576;
    ushort* w2 = w1 + 1048576;
    ushort* xp     = (ushort*)(wsb + 8912896);   // region A: 8 MiB
    ushort* t2     = xp;                         // A reuse
    ushort* a_ln   = (ushort*)(wsb + 17301504);  // region Br: 8 MiB
    ushort* yB     = a_ln;                       // Br reuse: y0 rows 0..8191
    ushort* qkvp   = (ushort*)(wsb + 25690112);  // region CD: 24 MiB
    ushort* attn_o = (ushort*)(wsb + 50855936);  // CD tail: 8 MiB
    ushort* h1c    = qkvp;                       // CD reuse: [8192][2048] 32 MiB
    ushort* yT     = (ushort*)(wsb + 59244544);  // region T: 24 MiB

    // 0. weight conversions
    cvtw_k<<<768,  256, 0, stream>>>(qkv_w,  wq, 196608);
    cvtw_k<<<256,  256, 0, stream>>>(proj_w, wp, 65536);
    cvtw_k<<<1024, 256, 0, stream>>>(pw1_w,  w1, 262144);
    cvtw_k<<<1024, 256, 0, stream>>>(pw2_w,  w2, 262144);
    cvtt_k<<<dim3(64, 16), 256, 0, stream>>>(ct_w, wc);
    // 1. depthwise conv + residual + avgpool
    dwpool_k<<<32 * 512, 256, 0, stream>>>(x, dw_w, dw_b, xp);
    // 2-3. LN1 stats + apply/transpose -> a_ln
    ln1_stats_k<<<128, 256, 0, stream>>>(xp, mean1, rstd1);
    ln1_apply_k<<<1024, 256, 0, stream>>>(xp, mean1, rstd1, ln1_g, ln1_b, a_ln);
    // 4. QKV gemm -> qkvp (Q/K permuted, V transposed)
    {
        GP p{}; p.A = a_ln; p.W = wq; p.bias = qkv_b; p.outB = qkvp; p.K = 512;
        mgemm_k<0, 128><<<dim3(12, 64), 256, 0, stream>>>(p);
    }
    // 5. attention (MFMA)
    attn_k<<<256, 256, 0, stream>>>(qkvp, mask_u, temp, attn_o);
    // 6. proj gemm (x2) -> t2
    {
        GP p{}; p.A = attn_o; p.W = wp; p.bias = proj_b; p.outB = t2; p.K = 512;
        mgemm_k<1, 128><<<dim3(4, 64), 256, 0, stream>>>(p);
    }
    // 7. convT gemm -> y0 (split yB/yT), channels-last
    {
        GP p{}; p.A = t2; p.W = wc; p.bias = ct_b;
        p.outB = yB; p.outB2 = yT; p.K = 512;
        mgemm_k<2, 128><<<dim3(16, 64), 256, 0, stream>>>(p);
    }
    // 8. LN2 fused stats+normalize in place
    ln2_fuse_k<<<8192, 256, 0, stream>>>(yB, yT, ln2_g, ln2_b);
    // 9. MLP in 4 chunks of 8192 rows
    for (int c = 0; c < 4; ++c) {
        int m0 = c * 8192;
        const ushort* yChunk = (c == 0) ? yB : (yT + (size_t)(m0 - 8192) * 512);
        {
            GP p{}; p.A = yChunk; p.W = w1; p.bias = pw1_b; p.outB = h1c; p.K = 512;
            mgemm_k<3, 128><<<dim3(16, 64), 256, 0, stream>>>(p);
        }
        {
            GP p{}; p.A = h1c; p.W = w2; p.bias = pw2_b;
            p.outF = (float*)d_out; p.inp = x; p.K = 2048; p.m0 = m0;
            mgemm_k<4, 64><<<dim3(8, 64), 256, 0, stream>>>(p);
        }
    }
}

// Round 5
// 613.582 us; speedup vs baseline: 1.1997x; 1.0090x over previous
//
#include <hip/hip_runtime.h>
#include <hip/hip_bf16.h>
#include <math.h>

typedef unsigned short ushort;
typedef __attribute__((ext_vector_type(8))) short short8;
typedef __attribute__((ext_vector_type(8))) unsigned short ushort8;
typedef __attribute__((ext_vector_type(4))) unsigned short ushort4v;
typedef __attribute__((ext_vector_type(4))) float f32x4;

__device__ __forceinline__ ushort f2bb(float v) {
    return __builtin_bit_cast(ushort, __float2bfloat16(v));
}
__device__ __forceinline__ float bf2f(ushort u) {
    return __bfloat162float(__builtin_bit_cast(__hip_bfloat16, u));
}
// async global->LDS 16B/lane; LDS dest = wave-uniform base + lane*16
__device__ __forceinline__ void gl2lds16(const ushort* g, ushort* l) {
    __builtin_amdgcn_global_load_lds(
        (const __attribute__((address_space(1))) unsigned int*)g,
        (__attribute__((address_space(3))) unsigned int*)l, 16, 0, 0);
}

// ---------------------------------------------------------------------------
// B=32, C=512, H=W=32, NH=8, dh=64, N=256 pooled, hidden=2048.
// r5: PW1 ported to 256x256/BK=64 8-wave counted-vmcnt kernel (mgemm256_pw1_k):
//   K staged in 4 half-units per tile; s_waitcnt vmcnt(4) + raw s_barrier
//   (loads in flight ACROSS barriers — no vmcnt(0) drain until tail);
//   s_setprio around MFMA cluster; 128 KiB dynamic LDS, 1 block/CU.
// r4 (kept): attn on MFMA, V stored transposed by QKV epilogue.
// r3 (kept): 128^2 dbuf GEMM for QKV/proj/convT/PW2.
// r2 (kept): chunk-XOR LDS swizzle (0 conflicts), full-line epilogue stores,
// XCD-band swizzle.
// ---------------------------------------------------------------------------

__global__ __launch_bounds__(256) void cvtw_k(const float* __restrict__ in,
                                              ushort* __restrict__ out, int n4) {
    int i = blockIdx.x * 256 + threadIdx.x;
    if (i >= n4) return;
    float4 v = ((const float4*)in)[i];
    ushort4v o;
    o.x = f2bb(v.x); o.y = f2bb(v.y); o.z = f2bb(v.z); o.w = f2bb(v.w);
    ((ushort4v*)out)[i] = o;
}

// ct_w [512][2048] fp32 -> [2048][512] bf16
__global__ __launch_bounds__(256) void cvtt_k(const float* __restrict__ in,
                                              ushort* __restrict__ out) {
    __shared__ float tl[32][33];
    int c0 = blockIdx.y * 32, j0 = blockIdx.x * 32;
    int tr = threadIdx.x >> 5, tc = threadIdx.x & 31;
#pragma unroll
    for (int p4 = 0; p4 < 4; ++p4)
        tl[tr + p4 * 8][tc] = in[(size_t)(c0 + tr + p4 * 8) * 2048 + j0 + tc];
    __syncthreads();
#pragma unroll
    for (int p4 = 0; p4 < 4; ++p4)
        out[(size_t)(j0 + tr + p4 * 8) * 512 + c0 + tc] = f2bb(tl[tc][tr + p4 * 8]);
}

// K1: depthwise 3x3 + bias + residual + 2x2 avgpool -> xp bf16 [B,C,16,16]
__global__ __launch_bounds__(256) void dwpool_k(const float* __restrict__ x,
                                                const float* __restrict__ dww,
                                                const float* __restrict__ dwb,
                                                ushort* __restrict__ xp) {
    int bc = blockIdx.x;
    int c = bc & 511;
    __shared__ float tile[32][33];
    __shared__ float w9[9];
    const float* xb = x + (size_t)bc * 1024;
    int tid = threadIdx.x;
    for (int i = tid; i < 1024; i += 256) tile[i >> 5][i & 31] = xb[i];
    if (tid < 9) w9[tid] = dww[c * 9 + tid];
    __syncthreads();
    float bv = dwb[c];
    int ph = tid >> 4, pw = tid & 15;
    float s = 0.f;
#pragma unroll
    for (int dy = 0; dy < 2; ++dy) {
#pragma unroll
        for (int dx = 0; dx < 2; ++dx) {
            int hh = 2 * ph + dy, ww = 2 * pw + dx;
            float a = bv + tile[hh][ww];
#pragma unroll
            for (int ky = 0; ky < 3; ++ky) {
                int yy = hh + ky - 1;
                if (yy < 0 || yy > 31) continue;
#pragma unroll
                for (int kx = 0; kx < 3; ++kx) {
                    int xx = ww + kx - 1;
                    if (xx < 0 || xx > 31) continue;
                    a += w9[ky * 3 + kx] * tile[yy][xx];
                }
            }
            s += a;
        }
    }
    xp[(size_t)bc * 256 + tid] = f2bb(0.25f * s);
}

// K2: LN1 stats per token over C=512; xp bf16 [b][c][n]
__global__ __launch_bounds__(256) void ln1_stats_k(const ushort* __restrict__ xp,
                                                   float* __restrict__ m1,
                                                   float* __restrict__ r1) {
    __shared__ float sh_s[4][64], sh_q[4][64];
    int blk = blockIdx.x;
    int b = blk >> 2;
    int n0 = (blk & 3) * 64;
    int t = threadIdx.x & 63, w = threadIdx.x >> 6;
    float s = 0.f, ss = 0.f;
    for (int i = 0; i < 128; ++i) {
        int c = w * 128 + i;
        float v = bf2f(xp[(size_t)(b * 512 + c) * 256 + n0 + t]);
        s += v; ss += v * v;
    }
    sh_s[w][t] = s; sh_q[w][t] = ss;
    __syncthreads();
    if (w == 0) {
        s  = sh_s[0][t] + sh_s[1][t] + sh_s[2][t] + sh_s[3][t];
        ss = sh_q[0][t] + sh_q[1][t] + sh_q[2][t] + sh_q[3][t];
        float m = s * (1.0f / 512.0f);
        m1[b * 256 + n0 + t] = m;
        r1[b * 256 + n0 + t] = rsqrtf(ss * (1.0f / 512.0f) - m * m + 1e-6f);
    }
}

// K3: LN1 apply + transpose: xp [b][c][n] -> a_ln [m][c] bf16 normalized
__global__ __launch_bounds__(256) void ln1_apply_k(const ushort* __restrict__ xp,
                                                   const float* __restrict__ m1,
                                                   const float* __restrict__ r1,
                                                   const float* __restrict__ g,
                                                   const float* __restrict__ beta,
                                                   ushort* __restrict__ a_ln) {
    __shared__ float tl[64][66];
    int blk = blockIdx.x;                 // b*32 + ct*4 + nt
    int b = blk >> 5, ct = (blk >> 2) & 7, nt = blk & 3;
    int t = threadIdx.x;
    int rq = t >> 6, nl = t & 63;
#pragma unroll
    for (int i = 0; i < 16; ++i) {
        int r = rq * 16 + i;
        int c = ct * 64 + r;
        tl[r][nl] = bf2f(xp[(size_t)(b * 512 + c) * 256 + nt * 64 + nl]);
    }
    __syncthreads();
    int r2 = t >> 2, cq = t & 3;
    int m = b * 256 + nt * 64 + r2;
    float mu = m1[m], rs = r1[m];
#pragma unroll
    for (int hh = 0; hh < 2; ++hh) {
        ushort8 o;
#pragma unroll
        for (int j = 0; j < 8; ++j) {
            int cl = cq * 16 + hh * 8 + j;
            int c = ct * 64 + cl;
            o[j] = f2bb((tl[cl][r2] - mu) * rs * g[c] + beta[c]);
        }
        *(ushort8*)&a_ln[(size_t)m * 512 + ct * 64 + cq * 16 + hh * 8] = o;
    }
}

// K7: LN2 fused stats+normalize, in place. y0 rows split across yB / yT.
__global__ __launch_bounds__(256) void ln2_fuse_k(ushort* __restrict__ yB,
                                                  ushort* __restrict__ yT,
                                                  const float* __restrict__ g,
                                                  const float* __restrict__ beta) {
    int w = threadIdx.x >> 6, lane = threadIdx.x & 63;
    int row = blockIdx.x * 4 + w;
    ushort* base = (row < 8192) ? (yB + (size_t)row * 512)
                                : (yT + (size_t)(row - 8192) * 512);
    ushort8 raw = *(ushort8*)&base[lane * 8];
    float v[8];
    float s = 0.f, ss = 0.f;
#pragma unroll
    for (int j = 0; j < 8; ++j) { v[j] = bf2f(raw[j]); s += v[j]; ss += v[j] * v[j]; }
#pragma unroll
    for (int off = 1; off < 64; off <<= 1) { s += __shfl_xor(s, off); ss += __shfl_xor(ss, off); }
    float mu = s * (1.0f / 512.0f);
    float rs = rsqrtf(ss * (1.0f / 512.0f) - mu * mu + 1e-6f);
    ushort8 o;
#pragma unroll
    for (int j = 0; j < 8; ++j) {
        int c = lane * 8 + j;
        o[j] = f2bb((v[j] - mu) * rs * g[c] + beta[c]);
    }
    *(ushort8*)&base[lane * 8] = o;
}

// ---------------------------------------------------------------------------
// MFMA GEMM (128xBN, BK=32, dbuf): out[m,j] = sum_k A[m,k]*W[j,k].
// MODE 0 QKV : out bf16 q/k [sect][bh][64 d][256 n]; V TRANSPOSED [bh][n][d]
// MODE 1 PROJ: out bf16 t2 = 2*(acc+bias), row-major LD=512
// MODE 2 CONVT: bf16 channels-last y0 (split base) + ct_b, 64B/pixel chunks
// MODE 4 PW2 : out fp32 d_out = inp + acc + bias (hw-fast, float4 ld/st)
// ---------------------------------------------------------------------------
struct GP {
    const ushort* A;
    const ushort* W;
    const float* bias;
    ushort* outB;
    ushort* outB2;
    float* outF;
    const float* inp;
    int K, m0;
};

template <int MODE, int BN>
__global__ __launch_bounds__(256) void mgemm_k(GP p) {
    constexpr int MT = (BN == 128) ? 4 : 2;   // 16-row m-tiles per wave
    constexpr int NT = 4;                     // 16-col n-tiles per wave
    constexpr int ATILE = 128 * 32;           // ushorts per A K-tile
    constexpr int BTILE = BN * 32;            // ushorts per B K-tile
    constexpr int SMEM_US = 2 * (ATILE + BTILE);  // dbuf; >= all epilogue needs
    __shared__ __align__(16) ushort smem[SMEM_US];
    int tid = threadIdx.x;
    int lane = tid & 63, w = tid >> 6;
    int lr = lane & 15, lq = lane >> 4;
    int mwoff = (BN == 128) ? (w >> 1) * 64 : w * 32;
    int nwoff = (BN == 128) ? (w & 1) * 64 : 0;
    // ---- XCD-band swizzle (bijective: nwg % 8 == 0 for all grids) ----
    int gx = gridDim.x;
    int wgid = blockIdx.y * gx + blockIdx.x;
    int cpx = (gx * gridDim.y) >> 3;          // blocks per XCD
    int swz = (wgid & 7) * cpx + (wgid >> 3);
    int bx = swz % gx, by = swz / gx;
    int mbase = by * 128, nbase = bx * BN;
    // staging: 16 rows x 4 chunks; source chunk permuted so linear LDS dest
    // holds the swizzled layout (rule #21)
    int lsub = lane >> 2;
    int cchunk = (lane & 3) ^ ((lsub >> 1) & 3);
    int lcol = cchunk * 8;
    int physc = lq ^ ((lr >> 1) & 3);         // frag-read phys chunk
    f32x4 acc[MT][NT] = {};

    auto stage = [&](int buf, int kb) {
        ushort* Ab = smem + buf * ATILE;
        ushort* Bb = smem + 2 * ATILE + buf * BTILE;
#pragma unroll
        for (int i = 0; i < 2; ++i) {
            int row = w * 32 + i * 16;
            gl2lds16(p.A + (size_t)(mbase + row + lsub) * p.K + kb + lcol,
                     &Ab[row * 32]);
        }
        if constexpr (BN == 128) {
#pragma unroll
            for (int i = 0; i < 2; ++i) {
                int row = w * 32 + i * 16;
                gl2lds16(p.W + (size_t)(nbase + row + lsub) * p.K + kb + lcol,
                         &Bb[row * 32]);
            }
        } else {
            int row = w * 16;
            gl2lds16(p.W + (size_t)(nbase + row + lsub) * p.K + kb + lcol,
                     &Bb[row * 32]);
        }
    };

    // prologue: stage tile 0, wait (implicit vmcnt(0) in syncthreads)
    stage(0, 0);
    __syncthreads();
    int nk = p.K >> 5;
    for (int t = 0; t < nk; ++t) {
        int cur = t & 1;
        if (t + 1 < nk) stage(cur ^ 1, (t + 1) << 5);   // prefetch next tile
        const ushort* Ac = smem + cur * ATILE;
        const ushort* Bc = smem + 2 * ATILE + cur * BTILE;
        short8 af[MT], bfr[NT];
#pragma unroll
        for (int tt = 0; tt < MT; ++tt)
            af[tt] = *(const short8*)&Ac[(mwoff + tt * 16 + lr) * 32 + physc * 8];
#pragma unroll
        for (int tt = 0; tt < NT; ++tt)
            bfr[tt] = *(const short8*)&Bc[(nwoff + tt * 16 + lr) * 32 + physc * 8];
#pragma unroll
        for (int i = 0; i < MT; ++i)
#pragma unroll
            for (int j = 0; j < NT; ++j)
                acc[i][j] = __builtin_amdgcn_mfma_f32_16x16x32_bf16(af[i], bfr[j], acc[i][j], 0, 0, 0);
        __syncthreads();   // drains vmcnt(0): next buffer ready for all waves
    }

    // ================= epilogues (LDS restage -> vector stores) =============
    if constexpr (MODE == 1 || MODE == 3) {
        // row-major bf16 out, cols fast. eb [128][64] us, chunk^(row&7) swizzle.
        const size_t LD = (MODE == 1) ? 512 : 2048;
        ushort* eb = (ushort*)smem;
#pragma unroll
        for (int h = 0; h < 2; ++h) {
            __syncthreads();
            if ((w & 1) == h) {
#pragma unroll
                for (int ti = 0; ti < MT; ++ti)
#pragma unroll
                    for (int tj = 0; tj < NT; ++tj)
#pragma unroll
                        for (int r = 0; r < 4; ++r) {
                            int row = mwoff + ti * 16 + lq * 4 + r;     // 0..127
                            int colh = tj * 16 + lr;                    // 0..63
                            float v = acc[ti][tj][r] + p.bias[nbase + h * 64 + colh];
                            if constexpr (MODE == 1) v *= 2.0f;
                            else v = 0.5f * v * (1.0f + erff(v * 0.70710678118654752f));
                            int ph = (colh >> 3) ^ (row & 7);
                            eb[row * 64 + ph * 8 + (colh & 7)] = f2bb(v);
                        }
            }
            __syncthreads();
#pragma unroll
            for (int i = 0; i < 4; ++i) {
                int row = i * 32 + (tid >> 3);
                int ch = tid & 7;
                int pch = ch ^ (row & 7);
                short8 d = *(short8*)&eb[row * 64 + pch * 8];
                *(short8*)&p.outB[(size_t)(mbase + row) * LD + nbase + h * 64 + ch * 8] = d;
            }
        }
    } else if constexpr (MODE == 0) {
        // QKV out. eb [32 c][136 row-us] per pc chunk.
        // Q/K (cg<1024): [sect][bh][d][n], n-fast stores.
        // V  (cg>=1024): TRANSPOSED [bh][n][d], d-fast stores.
        ushort* eb = (ushort*)smem;
        int b = mbase >> 8, n0 = mbase & 255;
#pragma unroll
        for (int pc = 0; pc < 4; ++pc) {
            __syncthreads();
            if ((w & 1) == (pc >> 1)) {
                int tjb = (pc & 1) * 2;
#pragma unroll
                for (int ti = 0; ti < MT; ++ti)
#pragma unroll
                    for (int tj2 = 0; tj2 < 2; ++tj2)
#pragma unroll
                        for (int r = 0; r < 4; ++r) {
                            int tj = tjb + tj2;
                            int row = mwoff + ti * 16 + lq * 4 + r;
                            int cl = tj2 * 16 + lr;                    // 0..31
                            float v = acc[ti][tj][r] + p.bias[nbase + pc * 32 + cl];
                            eb[cl * 136 + row] = f2bb(v);
                        }
            }
            __syncthreads();
            if (nbase < 1024) {
#pragma unroll
                for (int i = 0; i < 2; ++i) {
                    int dl = (tid >> 4) + 16 * i;                      // 0..31
                    int ch = tid & 15;                                 // 8-n chunk
                    short8 d = *(short8*)&eb[dl * 136 + ch * 8];
                    int cg = nbase + pc * 32 + dl;
                    int sect = cg >> 9, hh = (cg >> 6) & 7, dd = cg & 63;
                    size_t addr = ((size_t)(sect * 256 + b * 8 + hh) * 64 + dd) * 256 + n0 + ch * 8;
                    *(short8*)&p.outB[addr] = d;
                }
            } else {
                int cv = nbase + pc * 32 - 1024;   // V channel base (mult of 32)
                int bh2 = b * 8 + (cv >> 6);
                int d0 = cv & 63;                  // 0 or 32
#pragma unroll
                for (int i = 0; i < 2; ++i) {
                    int idx = i * 256 + tid;       // 0..511
                    int n = idx >> 2, oc = idx & 3;
                    ushort8 dv;
#pragma unroll
                    for (int j = 0; j < 8; ++j) dv[j] = eb[(oc * 8 + j) * 136 + n];
                    *(ushort8*)&p.outB[(size_t)8388608 + (size_t)bh2 * 16384 +
                                       (size_t)(n0 + n) * 64 + d0 + oc * 8] = dv;
                }
            }
        }
    } else if constexpr (MODE == 2) {
        // convT pixel scatter -> eb [256 pix][40 us], 64B/pixel stores.
        ushort* eb = (ushort*)smem;
        ushort* ybase = (mbase < 2048) ? p.outB : (p.outB2 - (size_t)8192 * 512);
        int obase = nbase >> 2;
#pragma unroll
        for (int hf = 0; hf < 2; ++hf) {
            __syncthreads();
            if ((w >> 1) == hf) {
#pragma unroll
                for (int ti = 0; ti < MT; ++ti)
#pragma unroll
                    for (int tj = 0; tj < NT; ++tj)
#pragma unroll
                        for (int r = 0; r < 4; ++r) {
                            int rl = (mwoff - hf * 64) + ti * 16 + lq * 4 + r; // 0..63
                            int cgl = nwoff + tj * 16 + lr;                    // 0..127
                            int o_l = cgl >> 2, pp = (cgl >> 1) & 1, qq = cgl & 1;
                            int pix = ((rl >> 4) * 2 + pp) * 32 + (rl & 15) * 2 + qq;
                            float v = acc[ti][tj][r] + p.bias[obase + o_l];
                            eb[pix * 40 + o_l] = f2bb(v);
                        }
            }
            __syncthreads();
            int hhbase = ((mbase & 255) >> 4) + hf * 4;
            int prb = (mbase >> 8) * 32 + 2 * hhbase;
#pragma unroll
            for (int i = 0; i < 4; ++i) {
                int pix = i * 64 + (tid >> 2);
                int ch = tid & 3;
                short8 d = *(short8*)&eb[pix * 40 + ch * 8];
                int pr = (prb + (pix >> 5)) * 32 + (pix & 31);
                *(short8*)&ybase[(size_t)pr * 512 + obase + ch * 8] = d;
            }
        }
    } else {
        // MODE 4: fp32 out, hw(=row)-fast. ef [32 c][132 row-f32], float4 I/O.
        float* ef = (float*)smem;
        int gm0 = p.m0 + mbase;
        int b = gm0 >> 10, hw0 = gm0 & 1023;
#pragma unroll
        for (int pc = 0; pc < 2; ++pc) {
            __syncthreads();
#pragma unroll
            for (int ti = 0; ti < MT; ++ti)
#pragma unroll
                for (int tj2 = 0; tj2 < 2; ++tj2)
#pragma unroll
                    for (int r = 0; r < 4; ++r) {
                        int tj = pc * 2 + tj2;
                        int row = mwoff + ti * 16 + lq * 4 + r;        // 0..127
                        int cl = tj2 * 16 + lr;                        // 0..31
                        ef[cl * 132 + row] = acc[ti][tj][r] + p.bias[nbase + pc * 32 + cl];
                    }
            __syncthreads();
#pragma unroll
            for (int i = 0; i < 4; ++i) {
                int cl = (tid >> 5) + 8 * i;                           // 0..31
                int ck = tid & 31;                                     // 4-row chunk
                float4 v4 = *(float4*)&ef[cl * 132 + ck * 4];
                int c = nbase + pc * 32 + cl;
                size_t idx = ((size_t)(b * 512 + c)) * 1024 + hw0 + ck * 4;
                float4 xin = *(const float4*)&p.inp[idx];
                float4 o4;
                o4.x = xin.x + v4.x; o4.y = xin.y + v4.y;
                o4.z = xin.z + v4.z; o4.w = xin.w + v4.w;
                *(float4*)&p.outF[idx] = o4;
            }
        }
    }
}

// ---------------------------------------------------------------------------
// r5: 256x256 / BK=64 / 8-wave counted-vmcnt GEMM, PW1 epilogue (gelu, LD 2048).
// LDS (dynamic 128 KiB): A[2 buf][2 kh][256 r][32 k] us | B same.
// Per tile: 4 stage units (A-k0,B-k0,A-k1,B-k1), 2 gl2lds16/thread each.
// Schedule per tile t (cur=t&1): per kstep kh: s_waitcnt vmcnt(4) [oldest unit
// pair landed; next-tile pair stays in flight]; s_barrier; ds_read frags;
// stage (t+1,kh) into buf^1; setprio(1); 32 MFMA; setprio(0).
// Tail: last kstep waits vmcnt(0). Never a mid-loop full drain.
// ---------------------------------------------------------------------------
__global__ __launch_bounds__(512, 2) void mgemm256_pw1_k(GP p) {
    extern __shared__ ushort smem[];
    ushort* Ab = smem;              // 32768 us (64 KiB)
    ushort* Bb = smem + 32768;      // 32768 us
    int tid = threadIdx.x;
    int lane = tid & 63, w = tid >> 6;      // 8 waves
    int lr = lane & 15, lq = lane >> 4;
    int wr = w >> 2, wc = w & 3;            // 2 x 4 wave grid
    // XCD-band swizzle (nwg = 256, %8 == 0)
    int gx = gridDim.x;
    int wgid = blockIdx.y * gx + blockIdx.x;
    int cpx = (gx * gridDim.y) >> 3;
    int swz = (wgid & 7) * cpx + (wgid >> 3);
    int bx = swz % gx, by = swz / gx;
    int mbase = by * 256, nbase = bx * 256;
    const int K = p.K;                      // 512
    // staging slots: 512 thr x 2 issues = 256 rows x 4 chunks per unit
    int srow0 = w * 32 + (lane >> 2);
    int schunk = lane & 3;
    f32x4 acc[8][4] = {};

    auto stageA = [&](int buf, int kh, int kb) {
        ushort* dst = Ab + buf * 16384 + kh * 8192;
#pragma unroll
        for (int i = 0; i < 2; ++i) {
            int row = srow0 + i * 16;
            int sc = schunk ^ ((row >> 1) & 3);
            gl2lds16(p.A + (size_t)(mbase + row) * K + kb + kh * 32 + sc * 8,
                     &dst[(w * 32 + i * 16) * 32]);
        }
    };
    auto stageB = [&](int buf, int kh, int kb) {
        ushort* dst = Bb + buf * 16384 + kh * 8192;
#pragma unroll
        for (int i = 0; i < 2; ++i) {
            int row = srow0 + i * 16;
            int sc = schunk ^ ((row >> 1) & 3);
            gl2lds16(p.W + (size_t)(nbase + row) * K + kb + kh * 32 + sc * 8,
                     &dst[(w * 32 + i * 16) * 32]);
        }
    };

// one kstep: wait(WN), barrier, frag reads, optional stage of (t+1,KH), MFMA
#define KSTEP256(KH, WN, DOSTAGE)                                             \
    {                                                                         \
        asm volatile("s_waitcnt vmcnt(" #WN ")" ::: "memory");                \
        __builtin_amdgcn_s_barrier();                                         \
        const ushort* Ak = Ab + cur * 16384 + (KH) * 8192;                    \
        const ushort* Bk = Bb + cur * 16384 + (KH) * 8192;                    \
        short8 af[8], bfv[4];                                                 \
        _Pragma("unroll")                                                     \
        for (int mt = 0; mt < 8; ++mt) {                                      \
            int row = wr * 128 + mt * 16 + lr;                                \
            af[mt] = *(const short8*)&Ak[row * 32 + ((lq ^ ((row >> 1) & 3)) << 3)]; \
        }                                                                     \
        _Pragma("unroll")                                                     \
        for (int nt = 0; nt < 4; ++nt) {                                      \
            int row = wc * 64 + nt * 16 + lr;                                 \
            bfv[nt] = *(const short8*)&Bk[row * 32 + ((lq ^ ((row >> 1) & 3)) << 3)]; \
        }                                                                     \
        if (DOSTAGE) { stageA(cur ^ 1, KH, kb2); stageB(cur ^ 1, KH, kb2); }  \
        __builtin_amdgcn_s_setprio(1);                                        \
        _Pragma("unroll")                                                     \
        for (int mt = 0; mt < 8; ++mt)                                        \
            _Pragma("unroll")                                                 \
            for (int nt = 0; nt < 4; ++nt)                                    \
                acc[mt][nt] = __builtin_amdgcn_mfma_f32_16x16x32_bf16(        \
                    af[mt], bfv[nt], acc[mt][nt], 0, 0, 0);                   \
        __builtin_amdgcn_s_setprio(0);                                        \
    }

    // prologue: tile 0, all 4 units (8 VMEM instr/thread in flight)
    stageA(0, 0, 0); stageB(0, 0, 0);
    stageA(0, 1, 0); stageB(0, 1, 0);
    int T = K >> 6;                          // 8 tiles
    int t = 0;
#pragma unroll 1
    for (; t < T - 1; ++t) {
        int cur = t & 1;
        int kb2 = (t + 1) << 6;
        KSTEP256(0, 4, 1)
        KSTEP256(1, 4, 1)
    }
    {
        int cur = t & 1;
        int kb2 = 0; (void)kb2;
        KSTEP256(0, 4, 0)
        KSTEP256(1, 0, 0)
    }
#undef KSTEP256

    // epilogue: two 128-row halves through LDS, full-line short8 stores
    ushort* eb = smem;                       // 32768 us reused
#pragma unroll
    for (int hf = 0; hf < 2; ++hf) {
        __syncthreads();
        if (wr == hf) {
#pragma unroll
            for (int mt = 0; mt < 8; ++mt)
#pragma unroll
                for (int nt = 0; nt < 4; ++nt)
#pragma unroll
                    for (int r = 0; r < 4; ++r) {
                        int rl = mt * 16 + lq * 4 + r;            // 0..127
                        int cl = wc * 64 + nt * 16 + lr;          // 0..255
                        float v = acc[mt][nt][r] + p.bias[nbase + cl];
                        v = 0.5f * v * (1.0f + erff(v * 0.70710678118654752f));
                        eb[rl * 256 + (((cl >> 3) ^ (rl & 7)) << 3) + (cl & 7)] = f2bb(v);
                    }
        }
        __syncthreads();
#pragma unroll
        for (int i = 0; i < 8; ++i) {
            int row = (tid >> 5) + i * 16;                        // 0..127
            int ch = tid & 31;
            short8 d = *(short8*)&eb[row * 256 + ((ch ^ (row & 7)) << 3)];
            *(short8*)&p.outB[(size_t)(mbase + hf * 128 + row) * 2048 + nbase + ch * 8] = d;
        }
    }
}

// ---------------------------------------------------------------------------
// K5: cosine attention per (b,h), MFMA. qkvp: Q,K [sect][bh][64 d][256 n];
// V transposed [bh][256 n][64 d]. Out attn_o [b*256+n][h*64+d] bf16.
// ---------------------------------------------------------------------------
__global__ __launch_bounds__(256) void attn_k(const ushort* __restrict__ qkvp,
                                              const float* __restrict__ mask_u,
                                              const float* __restrict__ temp,
                                              ushort* __restrict__ attn_out) {
    __shared__ float Sb[64 * 65];          // scores f32
    __shared__ ushort Pb[64 * 64];         // probs bf16, chunk^(row&7) swizzle
    __shared__ float fq[64], fk[64];
    int tid = threadIdx.x;
    int bh = blockIdx.x;
    int b = bh >> 3, h = bh & 7;
    const ushort* q  = qkvp + (size_t)bh * 16384;
    const ushort* k  = qkvp + 4194304 + (size_t)bh * 16384;
    const ushort* vt = qkvp + 8388608 + (size_t)bh * 16384;   // [256 n][64 d]
    int lane = tid & 63, w = tid >> 6;
    int lr = lane & 15, lq = lane >> 4;

    // ---- norms: 4 threads per row, 64 elems each ----
    {
        int row = tid >> 2, qd = tid & 3;
        const ushort* qr = q + row * 256 + qd * 64;
        const ushort* kr = k + row * 256 + qd * 64;
        float s = 0.f, t = 0.f;
#pragma unroll
        for (int i = 0; i < 8; ++i) {
            short8 a8 = *(const short8*)&qr[i * 8];
            short8 b8 = *(const short8*)&kr[i * 8];
#pragma unroll
            for (int j = 0; j < 8; ++j) {
                float fa = bf2f((ushort)a8[j]); s += fa * fa;
                float fb = bf2f((ushort)b8[j]); t += fb * fb;
            }
        }
        s += __shfl_xor(s, 1); s += __shfl_xor(s, 2);
        t += __shfl_xor(t, 1); t += __shfl_xor(t, 2);
        if (qd == 0) {
            fq[row] = 1.0f / fmaxf(sqrtf(s), 1e-12f);
            fk[row] = 1.0f / fmaxf(sqrtf(t), 1e-12f);
        }
    }
    __syncthreads();

    // ---- QK^T: 64x64, K=256. Wave quadrants 32x32 (2x2 tiles x 8 ksteps) ----
    int mq = (w >> 1) * 32, nq = (w & 1) * 32;
    f32x4 acc[2][2] = {};
    for (int kb = 0; kb < 256; kb += 32) {
        short8 af[2], bfr[2];
#pragma unroll
        for (int ti = 0; ti < 2; ++ti)
            af[ti] = *(const short8*)&q[(mq + ti * 16 + lr) * 256 + kb + lq * 8];
#pragma unroll
        for (int tj = 0; tj < 2; ++tj)
            bfr[tj] = *(const short8*)&k[(nq + tj * 16 + lr) * 256 + kb + lq * 8];
#pragma unroll
        for (int i = 0; i < 2; ++i)
#pragma unroll
            for (int j = 0; j < 2; ++j)
                acc[i][j] = __builtin_amdgcn_mfma_f32_16x16x32_bf16(af[i], bfr[j], acc[i][j], 0, 0, 0);
    }

    // ---- scale, mask, write S to LDS ----
    float tv = temp[h];
#pragma unroll
    for (int i = 0; i < 2; ++i)
#pragma unroll
        for (int r = 0; r < 4; ++r) {
            int d = mq + i * 16 + lq * 4 + r;
#pragma unroll
            for (int j = 0; j < 2; ++j) {
                int e = nq + j * 16 + lr;
                float sc = acc[i][j][r] * fq[d] * fk[e] * tv;
                float mu = mask_u[((size_t)bh * 64 + d) * 64 + e];
                if (mu < 0.2f) sc -= 1e12f;
                Sb[d * 65 + e] = sc;
            }
        }
    __syncthreads();

    // ---- softmax rows + pack P -> bf16 swizzled Pb ----
    {
        int row = tid >> 2, sub = tid & 3;
        float ev[16];
        float mx = -INFINITY;
#pragma unroll
        for (int i = 0; i < 16; ++i) { float s = Sb[row * 65 + sub * 16 + i]; ev[i] = s; mx = fmaxf(mx, s); }
        mx = fmaxf(mx, __shfl_xor(mx, 1));
        mx = fmaxf(mx, __shfl_xor(mx, 2));
        float sum = 0.f;
#pragma unroll
        for (int i = 0; i < 16; ++i) { ev[i] = expf(ev[i] - mx); sum += ev[i]; }
        sum += __shfl_xor(sum, 1);
        sum += __shfl_xor(sum, 2);
        float inv = 1.0f / sum;
        unsigned int* Pb32 = (unsigned int*)Pb;
#pragma unroll
        for (int kk = 0; kk < 8; ++kk) {
            unsigned int lo = f2bb(ev[2 * kk] * inv);
            unsigned int hi = f2bb(ev[2 * kk + 1] * inv);
            int c8 = sub * 2 + (kk >> 2);
            int ph = c8 ^ (row & 7);
            Pb32[row * 32 + ph * 4 + (kk & 3)] = (hi << 16) | lo;
        }
    }
    __syncthreads();

    // ---- PV: O[64 d][256 n] = P[64][64] * Vt[n][e]. Wave owns 64-n strip ----
    int nw = w * 64;
    f32x4 o[4][4] = {};
#pragma unroll
    for (int ks = 0; ks < 2; ++ks) {
        short8 pa[4];
#pragma unroll
        for (int mt = 0; mt < 4; ++mt) {
            int d = mt * 16 + lr;
            int ph = (ks * 4 + lq) ^ (d & 7);
            pa[mt] = *(const short8*)&Pb[d * 64 + ph * 8];
        }
#pragma unroll
        for (int nt = 0; nt < 4; ++nt) {
            short8 vb = *(const short8*)&vt[(size_t)(nw + nt * 16 + lr) * 64 + ks * 32 + lq * 8];
#pragma unroll
            for (int mt = 0; mt < 4; ++mt)
                o[mt][nt] = __builtin_amdgcn_mfma_f32_16x16x32_bf16(pa[mt], vb, o[mt][nt], 0, 0, 0);
        }
    }

    // ---- store O: attn_o[b*256+n][h*64+d], 8B packed per (mt,nt) ----
#pragma unroll
    for (int mt = 0; mt < 4; ++mt) {
        int d0 = mt * 16 + lq * 4;
#pragma unroll
        for (int nt = 0; nt < 4; ++nt) {
            int n = nw + nt * 16 + lr;
            ushort4v ov;
#pragma unroll
            for (int r = 0; r < 4; ++r) ov[r] = f2bb(o[mt][nt][r]);
            *(ushort4v*)&attn_out[((size_t)(b * 256 + n)) * 512 + h * 64 + d0] = ov;
        }
    }
}

// ---------------------------------------------------------------------------
extern "C" void kernel_launch(void* const* d_in, const int* in_sizes, int n_in,
                              void* d_out, int out_size, void* d_ws, size_t ws_size,
                              hipStream_t stream) {
    const float* x      = (const float*)d_in[0];
    const float* mask_u = (const float*)d_in[1];
    const float* dw_w   = (const float*)d_in[2];
    const float* dw_b   = (const float*)d_in[3];
    const float* ln1_g  = (const float*)d_in[4];
    const float* ln1_b  = (const float*)d_in[5];
    const float* qkv_w  = (const float*)d_in[6];
    const float* qkv_b  = (const float*)d_in[7];
    const float* temp   = (const float*)d_in[8];
    const float* proj_w = (const float*)d_in[9];
    const float* proj_b = (const float*)d_in[10];
    const float* ct_w   = (const float*)d_in[11];
    const float* ct_b   = (const float*)d_in[12];
    const float* ln2_g  = (const float*)d_in[13];
    const float* ln2_b  = (const float*)d_in[14];
    const float* pw1_w  = (const float*)d_in[15];
    const float* pw1_b  = (const float*)d_in[16];
    const float* pw2_w  = (const float*)d_in[17];
    const float* pw2_b  = (const float*)d_in[18];

    char* wsb = (char*)d_ws;
    float* mean1 = (float*)wsb;
    float* rstd1 = mean1 + 8192;
    ushort* wq = (ushort*)(wsb + 524288);
    ushort* wp = wq + 786432;
    ushort* wc = wp + 262144;
    ushort* w1 = wc + 1048576;
    ushort* w2 = w1 + 1048576;
    ushort* xp     = (ushort*)(wsb + 8912896);   // region A: 8 MiB
    ushort* t2     = xp;                         // A reuse
    ushort* a_ln   = (ushort*)(wsb + 17301504);  // region Br: 8 MiB
    ushort* yB     = a_ln;                       // Br reuse: y0 rows 0..8191
    ushort* qkvp   = (ushort*)(wsb + 25690112);  // region CD: 24 MiB
    ushort* attn_o = (ushort*)(wsb + 50855936);  // CD tail: 8 MiB
    ushort* h1c    = qkvp;                       // CD reuse: [8192][2048] 32 MiB
    ushort* yT     = (ushort*)(wsb + 59244544);  // region T: 24 MiB

    // allow 128 KiB dynamic LDS for the 256^2 kernel (idempotent)
    hipFuncSetAttribute((const void*)mgemm256_pw1_k,
                        hipFuncAttributeMaxDynamicSharedMemorySize, 131072);

    // 0. weight conversions
    cvtw_k<<<768,  256, 0, stream>>>(qkv_w,  wq, 196608);
    cvtw_k<<<256,  256, 0, stream>>>(proj_w, wp, 65536);
    cvtw_k<<<1024, 256, 0, stream>>>(pw1_w,  w1, 262144);
    cvtw_k<<<1024, 256, 0, stream>>>(pw2_w,  w2, 262144);
    cvtt_k<<<dim3(64, 16), 256, 0, stream>>>(ct_w, wc);
    // 1. depthwise conv + residual + avgpool
    dwpool_k<<<32 * 512, 256, 0, stream>>>(x, dw_w, dw_b, xp);
    // 2-3. LN1 stats + apply/transpose -> a_ln
    ln1_stats_k<<<128, 256, 0, stream>>>(xp, mean1, rstd1);
    ln1_apply_k<<<1024, 256, 0, stream>>>(xp, mean1, rstd1, ln1_g, ln1_b, a_ln);
    // 4. QKV gemm -> qkvp (Q/K permuted, V transposed)
    {
        GP p{}; p.A = a_ln; p.W = wq; p.bias = qkv_b; p.outB = qkvp; p.K = 512;
        mgemm_k<0, 128><<<dim3(12, 64), 256, 0, stream>>>(p);
    }
    // 5. attention (MFMA)
    attn_k<<<256, 256, 0, stream>>>(qkvp, mask_u, temp, attn_o);
    // 6. proj gemm (x2) -> t2
    {
        GP p{}; p.A = attn_o; p.W = wp; p.bias = proj_b; p.outB = t2; p.K = 512;
        mgemm_k<1, 128><<<dim3(4, 64), 256, 0, stream>>>(p);
    }
    // 7. convT gemm -> y0 (split yB/yT), channels-last
    {
        GP p{}; p.A = t2; p.W = wc; p.bias = ct_b;
        p.outB = yB; p.outB2 = yT; p.K = 512;
        mgemm_k<2, 128><<<dim3(16, 64), 256, 0, stream>>>(p);
    }
    // 8. LN2 fused stats+normalize in place
    ln2_fuse_k<<<8192, 256, 0, stream>>>(yB, yT, ln2_g, ln2_b);
    // 9. MLP in 4 chunks of 8192 rows
    for (int c = 0; c < 4; ++c) {
        int m0 = c * 8192;
        const ushort* yChunk = (c == 0) ? yB : (yT + (size_t)(m0 - 8192) * 512);
        {
            GP p{}; p.A = yChunk; p.W = w1; p.bias = pw1_b; p.outB = h1c; p.K = 512;
            mgemm256_pw1_k<<<dim3(8, 32), 512, 131072, stream>>>(p);
        }
        {
            GP p{}; p.A = h1c; p.W = w2; p.bias = pw2_b;
            p.outF = (float*)d_out; p.inp = x; p.K = 2048; p.m0 = m0;
            mgemm_k<4, 64><<<dim3(8, 64), 256, 0, stream>>>(p);
        }
    }
}

// Round 6
// 589.558 us; speedup vs baseline: 1.2486x; 1.0407x over previous
//
#include <hip/hip_runtime.h>
#include <hip/hip_bf16.h>
#include <math.h>

typedef unsigned short ushort;
typedef __attribute__((ext_vector_type(8))) short short8;
typedef __attribute__((ext_vector_type(8))) unsigned short ushort8;
typedef __attribute__((ext_vector_type(4))) unsigned short ushort4v;
typedef __attribute__((ext_vector_type(4))) float f32x4;

__device__ __forceinline__ ushort f2bb(float v) {
    return __builtin_bit_cast(ushort, __float2bfloat16(v));
}
__device__ __forceinline__ float bf2f(ushort u) {
    return __bfloat162float(__builtin_bit_cast(__hip_bfloat16, u));
}
// async global->LDS 16B/lane; LDS dest = wave-uniform base + lane*16
__device__ __forceinline__ void gl2lds16(const ushort* g, ushort* l) {
    __builtin_amdgcn_global_load_lds(
        (const __attribute__((address_space(1))) unsigned int*)g,
        (__attribute__((address_space(3))) unsigned int*)l, 16, 0, 0);
}

// ---------------------------------------------------------------------------
// B=32, C=512, H=W=32, NH=8, dh=64, N=256 pooled, hidden=2048.
// r6: MLP fused into ONE kernel (mlp_fused_k): per 64-row block, y-rows staged
//   once in LDS; hidden looped in 8x256 chunks: GEMM1 (W1 frags register-
//   direct from L2) -> gelu -> h via 32KB LDS -> GEMM2 accumulates O in regs
//   -> fused bias+residual fp32 epilogue. Kills h1c (256MB round-trip), 6
//   dispatch tails, and moves 137 GFLOP into one dispatch (m102 shape curve:
//   17-GFLOP dispatches cap ~300 TF; 137-GFLOP class reaches ~900).
// r4 (kept): attn on MFMA, V stored transposed by QKV epilogue.
// r3 (kept): 128^2 dbuf GEMM for QKV/proj/convT.
// r2 (kept): chunk-XOR LDS swizzle (0 conflicts), full-line epilogue stores,
// XCD-band swizzle.
// ---------------------------------------------------------------------------

__global__ __launch_bounds__(256) void cvtw_k(const float* __restrict__ in,
                                              ushort* __restrict__ out, int n4) {
    int i = blockIdx.x * 256 + threadIdx.x;
    if (i >= n4) return;
    float4 v = ((const float4*)in)[i];
    ushort4v o;
    o.x = f2bb(v.x); o.y = f2bb(v.y); o.z = f2bb(v.z); o.w = f2bb(v.w);
    ((ushort4v*)out)[i] = o;
}

// ct_w [512][2048] fp32 -> [2048][512] bf16
__global__ __launch_bounds__(256) void cvtt_k(const float* __restrict__ in,
                                              ushort* __restrict__ out) {
    __shared__ float tl[32][33];
    int c0 = blockIdx.y * 32, j0 = blockIdx.x * 32;
    int tr = threadIdx.x >> 5, tc = threadIdx.x & 31;
#pragma unroll
    for (int p4 = 0; p4 < 4; ++p4)
        tl[tr + p4 * 8][tc] = in[(size_t)(c0 + tr + p4 * 8) * 2048 + j0 + tc];
    __syncthreads();
#pragma unroll
    for (int p4 = 0; p4 < 4; ++p4)
        out[(size_t)(j0 + tr + p4 * 8) * 512 + c0 + tc] = f2bb(tl[tc][tr + p4 * 8]);
}

// K1: depthwise 3x3 + bias + residual + 2x2 avgpool -> xp bf16 [B,C,16,16]
__global__ __launch_bounds__(256) void dwpool_k(const float* __restrict__ x,
                                                const float* __restrict__ dww,
                                                const float* __restrict__ dwb,
                                                ushort* __restrict__ xp) {
    int bc = blockIdx.x;
    int c = bc & 511;
    __shared__ float tile[32][33];
    __shared__ float w9[9];
    const float* xb = x + (size_t)bc * 1024;
    int tid = threadIdx.x;
    for (int i = tid; i < 1024; i += 256) tile[i >> 5][i & 31] = xb[i];
    if (tid < 9) w9[tid] = dww[c * 9 + tid];
    __syncthreads();
    float bv = dwb[c];
    int ph = tid >> 4, pw = tid & 15;
    float s = 0.f;
#pragma unroll
    for (int dy = 0; dy < 2; ++dy) {
#pragma unroll
        for (int dx = 0; dx < 2; ++dx) {
            int hh = 2 * ph + dy, ww = 2 * pw + dx;
            float a = bv + tile[hh][ww];
#pragma unroll
            for (int ky = 0; ky < 3; ++ky) {
                int yy = hh + ky - 1;
                if (yy < 0 || yy > 31) continue;
#pragma unroll
                for (int kx = 0; kx < 3; ++kx) {
                    int xx = ww + kx - 1;
                    if (xx < 0 || xx > 31) continue;
                    a += w9[ky * 3 + kx] * tile[yy][xx];
                }
            }
            s += a;
        }
    }
    xp[(size_t)bc * 256 + tid] = f2bb(0.25f * s);
}

// K2: LN1 stats per token over C=512; xp bf16 [b][c][n]
__global__ __launch_bounds__(256) void ln1_stats_k(const ushort* __restrict__ xp,
                                                   float* __restrict__ m1,
                                                   float* __restrict__ r1) {
    __shared__ float sh_s[4][64], sh_q[4][64];
    int blk = blockIdx.x;
    int b = blk >> 2;
    int n0 = (blk & 3) * 64;
    int t = threadIdx.x & 63, w = threadIdx.x >> 6;
    float s = 0.f, ss = 0.f;
    for (int i = 0; i < 128; ++i) {
        int c = w * 128 + i;
        float v = bf2f(xp[(size_t)(b * 512 + c) * 256 + n0 + t]);
        s += v; ss += v * v;
    }
    sh_s[w][t] = s; sh_q[w][t] = ss;
    __syncthreads();
    if (w == 0) {
        s  = sh_s[0][t] + sh_s[1][t] + sh_s[2][t] + sh_s[3][t];
        ss = sh_q[0][t] + sh_q[1][t] + sh_q[2][t] + sh_q[3][t];
        float m = s * (1.0f / 512.0f);
        m1[b * 256 + n0 + t] = m;
        r1[b * 256 + n0 + t] = rsqrtf(ss * (1.0f / 512.0f) - m * m + 1e-6f);
    }
}

// K3: LN1 apply + transpose: xp [b][c][n] -> a_ln [m][c] bf16 normalized
__global__ __launch_bounds__(256) void ln1_apply_k(const ushort* __restrict__ xp,
                                                   const float* __restrict__ m1,
                                                   const float* __restrict__ r1,
                                                   const float* __restrict__ g,
                                                   const float* __restrict__ beta,
                                                   ushort* __restrict__ a_ln) {
    __shared__ float tl[64][66];
    int blk = blockIdx.x;                 // b*32 + ct*4 + nt
    int b = blk >> 5, ct = (blk >> 2) & 7, nt = blk & 3;
    int t = threadIdx.x;
    int rq = t >> 6, nl = t & 63;
#pragma unroll
    for (int i = 0; i < 16; ++i) {
        int r = rq * 16 + i;
        int c = ct * 64 + r;
        tl[r][nl] = bf2f(xp[(size_t)(b * 512 + c) * 256 + nt * 64 + nl]);
    }
    __syncthreads();
    int r2 = t >> 2, cq = t & 3;
    int m = b * 256 + nt * 64 + r2;
    float mu = m1[m], rs = r1[m];
#pragma unroll
    for (int hh = 0; hh < 2; ++hh) {
        ushort8 o;
#pragma unroll
        for (int j = 0; j < 8; ++j) {
            int cl = cq * 16 + hh * 8 + j;
            int c = ct * 64 + cl;
            o[j] = f2bb((tl[cl][r2] - mu) * rs * g[c] + beta[c]);
        }
        *(ushort8*)&a_ln[(size_t)m * 512 + ct * 64 + cq * 16 + hh * 8] = o;
    }
}

// K7: LN2 fused stats+normalize, in place. y0 rows split across yB / yT.
__global__ __launch_bounds__(256) void ln2_fuse_k(ushort* __restrict__ yB,
                                                  ushort* __restrict__ yT,
                                                  const float* __restrict__ g,
                                                  const float* __restrict__ beta) {
    int w = threadIdx.x >> 6, lane = threadIdx.x & 63;
    int row = blockIdx.x * 4 + w;
    ushort* base = (row < 8192) ? (yB + (size_t)row * 512)
                                : (yT + (size_t)(row - 8192) * 512);
    ushort8 raw = *(ushort8*)&base[lane * 8];
    float v[8];
    float s = 0.f, ss = 0.f;
#pragma unroll
    for (int j = 0; j < 8; ++j) { v[j] = bf2f(raw[j]); s += v[j]; ss += v[j] * v[j]; }
#pragma unroll
    for (int off = 1; off < 64; off <<= 1) { s += __shfl_xor(s, off); ss += __shfl_xor(ss, off); }
    float mu = s * (1.0f / 512.0f);
    float rs = rsqrtf(ss * (1.0f / 512.0f) - mu * mu + 1e-6f);
    ushort8 o;
#pragma unroll
    for (int j = 0; j < 8; ++j) {
        int c = lane * 8 + j;
        o[j] = f2bb((v[j] - mu) * rs * g[c] + beta[c]);
    }
    *(ushort8*)&base[lane * 8] = o;
}

// ---------------------------------------------------------------------------
// MFMA GEMM (128xBN, BK=32, dbuf): out[m,j] = sum_k A[m,k]*W[j,k].
// MODE 0 QKV : out bf16 q/k [sect][bh][64 d][256 n]; V TRANSPOSED [bh][n][d]
// MODE 1 PROJ: out bf16 t2 = 2*(acc+bias), row-major LD=512
// MODE 2 CONVT: bf16 channels-last y0 (split base) + ct_b, 64B/pixel chunks
// ---------------------------------------------------------------------------
struct GP {
    const ushort* A;
    const ushort* W;
    const float* bias;
    ushort* outB;
    ushort* outB2;
    float* outF;
    const float* inp;
    int K, m0;
};

template <int MODE, int BN>
__global__ __launch_bounds__(256) void mgemm_k(GP p) {
    constexpr int MT = (BN == 128) ? 4 : 2;   // 16-row m-tiles per wave
    constexpr int NT = 4;                     // 16-col n-tiles per wave
    constexpr int ATILE = 128 * 32;           // ushorts per A K-tile
    constexpr int BTILE = BN * 32;            // ushorts per B K-tile
    constexpr int SMEM_US = 2 * (ATILE + BTILE);  // dbuf; >= all epilogue needs
    __shared__ __align__(16) ushort smem[SMEM_US];
    int tid = threadIdx.x;
    int lane = tid & 63, w = tid >> 6;
    int lr = lane & 15, lq = lane >> 4;
    int mwoff = (BN == 128) ? (w >> 1) * 64 : w * 32;
    int nwoff = (BN == 128) ? (w & 1) * 64 : 0;
    // ---- XCD-band swizzle (bijective: nwg % 8 == 0 for all grids) ----
    int gx = gridDim.x;
    int wgid = blockIdx.y * gx + blockIdx.x;
    int cpx = (gx * gridDim.y) >> 3;          // blocks per XCD
    int swz = (wgid & 7) * cpx + (wgid >> 3);
    int bx = swz % gx, by = swz / gx;
    int mbase = by * 128, nbase = bx * BN;
    // staging: 16 rows x 4 chunks; source chunk permuted so linear LDS dest
    // holds the swizzled layout (rule #21)
    int lsub = lane >> 2;
    int cchunk = (lane & 3) ^ ((lsub >> 1) & 3);
    int lcol = cchunk * 8;
    int physc = lq ^ ((lr >> 1) & 3);         // frag-read phys chunk
    f32x4 acc[MT][NT] = {};

    auto stage = [&](int buf, int kb) {
        ushort* Ab = smem + buf * ATILE;
        ushort* Bb = smem + 2 * ATILE + buf * BTILE;
#pragma unroll
        for (int i = 0; i < 2; ++i) {
            int row = w * 32 + i * 16;
            gl2lds16(p.A + (size_t)(mbase + row + lsub) * p.K + kb + lcol,
                     &Ab[row * 32]);
        }
        if constexpr (BN == 128) {
#pragma unroll
            for (int i = 0; i < 2; ++i) {
                int row = w * 32 + i * 16;
                gl2lds16(p.W + (size_t)(nbase + row + lsub) * p.K + kb + lcol,
                         &Bb[row * 32]);
            }
        } else {
            int row = w * 16;
            gl2lds16(p.W + (size_t)(nbase + row + lsub) * p.K + kb + lcol,
                     &Bb[row * 32]);
        }
    };

    // prologue: stage tile 0, wait (implicit vmcnt(0) in syncthreads)
    stage(0, 0);
    __syncthreads();
    int nk = p.K >> 5;
    for (int t = 0; t < nk; ++t) {
        int cur = t & 1;
        if (t + 1 < nk) stage(cur ^ 1, (t + 1) << 5);   // prefetch next tile
        const ushort* Ac = smem + cur * ATILE;
        const ushort* Bc = smem + 2 * ATILE + cur * BTILE;
        short8 af[MT], bfr[NT];
#pragma unroll
        for (int tt = 0; tt < MT; ++tt)
            af[tt] = *(const short8*)&Ac[(mwoff + tt * 16 + lr) * 32 + physc * 8];
#pragma unroll
        for (int tt = 0; tt < NT; ++tt)
            bfr[tt] = *(const short8*)&Bc[(nwoff + tt * 16 + lr) * 32 + physc * 8];
#pragma unroll
        for (int i = 0; i < MT; ++i)
#pragma unroll
            for (int j = 0; j < NT; ++j)
                acc[i][j] = __builtin_amdgcn_mfma_f32_16x16x32_bf16(af[i], bfr[j], acc[i][j], 0, 0, 0);
        __syncthreads();   // drains vmcnt(0): next buffer ready for all waves
    }

    // ================= epilogues (LDS restage -> vector stores) =============
    if constexpr (MODE == 1 || MODE == 3) {
        // row-major bf16 out, cols fast. eb [128][64] us, chunk^(row&7) swizzle.
        const size_t LD = (MODE == 1) ? 512 : 2048;
        ushort* eb = (ushort*)smem;
#pragma unroll
        for (int h = 0; h < 2; ++h) {
            __syncthreads();
            if ((w & 1) == h) {
#pragma unroll
                for (int ti = 0; ti < MT; ++ti)
#pragma unroll
                    for (int tj = 0; tj < NT; ++tj)
#pragma unroll
                        for (int r = 0; r < 4; ++r) {
                            int row = mwoff + ti * 16 + lq * 4 + r;     // 0..127
                            int colh = tj * 16 + lr;                    // 0..63
                            float v = acc[ti][tj][r] + p.bias[nbase + h * 64 + colh];
                            if constexpr (MODE == 1) v *= 2.0f;
                            else v = 0.5f * v * (1.0f + erff(v * 0.70710678118654752f));
                            int ph = (colh >> 3) ^ (row & 7);
                            eb[row * 64 + ph * 8 + (colh & 7)] = f2bb(v);
                        }
            }
            __syncthreads();
#pragma unroll
            for (int i = 0; i < 4; ++i) {
                int row = i * 32 + (tid >> 3);
                int ch = tid & 7;
                int pch = ch ^ (row & 7);
                short8 d = *(short8*)&eb[row * 64 + pch * 8];
                *(short8*)&p.outB[(size_t)(mbase + row) * LD + nbase + h * 64 + ch * 8] = d;
            }
        }
    } else if constexpr (MODE == 0) {
        // QKV out. eb [32 c][136 row-us] per pc chunk.
        // Q/K (cg<1024): [sect][bh][d][n], n-fast stores.
        // V  (cg>=1024): TRANSPOSED [bh][n][d], d-fast stores.
        ushort* eb = (ushort*)smem;
        int b = mbase >> 8, n0 = mbase & 255;
#pragma unroll
        for (int pc = 0; pc < 4; ++pc) {
            __syncthreads();
            if ((w & 1) == (pc >> 1)) {
                int tjb = (pc & 1) * 2;
#pragma unroll
                for (int ti = 0; ti < MT; ++ti)
#pragma unroll
                    for (int tj2 = 0; tj2 < 2; ++tj2)
#pragma unroll
                        for (int r = 0; r < 4; ++r) {
                            int tj = tjb + tj2;
                            int row = mwoff + ti * 16 + lq * 4 + r;
                            int cl = tj2 * 16 + lr;                    // 0..31
                            float v = acc[ti][tj][r] + p.bias[nbase + pc * 32 + cl];
                            eb[cl * 136 + row] = f2bb(v);
                        }
            }
            __syncthreads();
            if (nbase < 1024) {
#pragma unroll
                for (int i = 0; i < 2; ++i) {
                    int dl = (tid >> 4) + 16 * i;                      // 0..31
                    int ch = tid & 15;                                 // 8-n chunk
                    short8 d = *(short8*)&eb[dl * 136 + ch * 8];
                    int cg = nbase + pc * 32 + dl;
                    int sect = cg >> 9, hh = (cg >> 6) & 7, dd = cg & 63;
                    size_t addr = ((size_t)(sect * 256 + b * 8 + hh) * 64 + dd) * 256 + n0 + ch * 8;
                    *(short8*)&p.outB[addr] = d;
                }
            } else {
                int cv = nbase + pc * 32 - 1024;   // V channel base (mult of 32)
                int bh2 = b * 8 + (cv >> 6);
                int d0 = cv & 63;                  // 0 or 32
#pragma unroll
                for (int i = 0; i < 2; ++i) {
                    int idx = i * 256 + tid;       // 0..511
                    int n = idx >> 2, oc = idx & 3;
                    ushort8 dv;
#pragma unroll
                    for (int j = 0; j < 8; ++j) dv[j] = eb[(oc * 8 + j) * 136 + n];
                    *(ushort8*)&p.outB[(size_t)8388608 + (size_t)bh2 * 16384 +
                                       (size_t)(n0 + n) * 64 + d0 + oc * 8] = dv;
                }
            }
        }
    } else if constexpr (MODE == 2) {
        // convT pixel scatter -> eb [256 pix][40 us], 64B/pixel stores.
        ushort* eb = (ushort*)smem;
        ushort* ybase = (mbase < 2048) ? p.outB : (p.outB2 - (size_t)8192 * 512);
        int obase = nbase >> 2;
#pragma unroll
        for (int hf = 0; hf < 2; ++hf) {
            __syncthreads();
            if ((w >> 1) == hf) {
#pragma unroll
                for (int ti = 0; ti < MT; ++ti)
#pragma unroll
                    for (int tj = 0; tj < NT; ++tj)
#pragma unroll
                        for (int r = 0; r < 4; ++r) {
                            int rl = (mwoff - hf * 64) + ti * 16 + lq * 4 + r; // 0..63
                            int cgl = nwoff + tj * 16 + lr;                    // 0..127
                            int o_l = cgl >> 2, pp = (cgl >> 1) & 1, qq = cgl & 1;
                            int pix = ((rl >> 4) * 2 + pp) * 32 + (rl & 15) * 2 + qq;
                            float v = acc[ti][tj][r] + p.bias[obase + o_l];
                            eb[pix * 40 + o_l] = f2bb(v);
                        }
            }
            __syncthreads();
            int hhbase = ((mbase & 255) >> 4) + hf * 4;
            int prb = (mbase >> 8) * 32 + 2 * hhbase;
#pragma unroll
            for (int i = 0; i < 4; ++i) {
                int pix = i * 64 + (tid >> 2);
                int ch = tid & 3;
                short8 d = *(short8*)&eb[pix * 40 + ch * 8];
                int pr = (prb + (pix >> 5)) * 32 + (pix & 31);
                *(short8*)&ybase[(size_t)pr * 512 + obase + ch * 8] = d;
            }
        }
    }
}

// ---------------------------------------------------------------------------
// r6: fused MLP. One dispatch, 512 blocks x 512 thr, 64 y-rows per block.
// d_out = inp + gelu(y @ W1^T + b1) @ W2^T + b2, y bf16 [32768][512] (yB/yT).
// Per block: y-rows staged ONCE into Asm [64][512] (row-XOR chunk swizzle,
// pre-swizzled gl2lds source, rule #21). Hidden loop: 8 chunks of 256:
//   GEMM1: acc1[4mt][2nt] (wave owns 32 h-cols), W1 frags REGISTER-DIRECT
//   from global (L2-resident, no LDS staging choreography);
//   gelu -> Hsm [64][256] bf16 (swizzled); barrier;
//   GEMM2: acc2[4mt][4nt] += Hsm x W2 frags (register-direct).
// Epilogue: fp32 float4 read-add-write vs inp (hw-contiguous per lane).
// MFMA floor 55 us for the whole 137-GFLOP MLP (was 8 dispatches ~440 us).
// ---------------------------------------------------------------------------
__global__ __launch_bounds__(512) void mlp_fused_k(
    const ushort* __restrict__ yB, const ushort* __restrict__ yT,
    const ushort* __restrict__ w1, const ushort* __restrict__ w2,
    const float* __restrict__ b1, const float* __restrict__ b2,
    const float* __restrict__ inp, float* __restrict__ outF) {
    __shared__ __align__(16) ushort Asm[64 * 512];   // 64 KiB
    __shared__ __align__(16) ushort Hsm[64 * 256];   // 32 KiB
    int tid = threadIdx.x;
    int lane = tid & 63, w = tid >> 6;               // 8 waves
    int lr = lane & 15, lq = lane >> 4;
    // XCD-band swizzle over 512 blocks (512 % 8 == 0, bijective)
    int wgid = blockIdx.x;
    int swz = (wgid & 7) * 64 + (wgid >> 3);
    int mbase = swz * 64;
    const ushort* yb = (mbase < 8192) ? (yB + (size_t)mbase * 512)
                                      : (yT + (size_t)(mbase - 8192) * 512);
    // stage A: one full 1KiB row per gl2lds instr; lane l holds phys chunk l,
    // source chunk l^(row&7) -> LDS holds swizzled layout with linear dest.
#pragma unroll
    for (int j = 0; j < 8; ++j) {
        int row = w * 8 + j;
        int sc = lane ^ (row & 7);
        gl2lds16(yb + (size_t)row * 512 + sc * 8, &Asm[row * 512]);
    }
    int ocol0 = w * 64;          // GEMM2 wave out-col strip
    int hcol0 = w * 32;          // GEMM1 wave h-col strip
    float b2v[4];
#pragma unroll
    for (int nt = 0; nt < 4; ++nt) b2v[nt] = b2[ocol0 + nt * 16 + lr];
    asm volatile("s_waitcnt vmcnt(0)" ::: "memory");
    __syncthreads();

    f32x4 acc2[4][4] = {};
#pragma unroll 1
    for (int hb = 0; hb < 8; ++hb) {
        // ---- GEMM1: h-cols hcol0..+31, K=512 from Asm + register-direct W1 ----
        f32x4 acc1[4][2] = {};
#pragma unroll
        for (int kh = 0; kh < 16; ++kh) {
            short8 bf1[2];
#pragma unroll
            for (int nt = 0; nt < 2; ++nt)
                bf1[nt] = *(const short8*)&w1[(size_t)(hb * 256 + hcol0 + nt * 16 + lr) * 512 + kh * 32 + lq * 8];
#pragma unroll
            for (int mt = 0; mt < 4; ++mt) {
                int row = mt * 16 + lr;
                int c = kh * 4 + lq;
                short8 af = *(const short8*)&Asm[row * 512 + ((c ^ (row & 7)) << 3)];
#pragma unroll
                for (int nt = 0; nt < 2; ++nt)
                    acc1[mt][nt] = __builtin_amdgcn_mfma_f32_16x16x32_bf16(af, bf1[nt], acc1[mt][nt], 0, 0, 0);
            }
        }
        // ---- gelu + pack h into Hsm (swizzled). C: row=lq*4+r, col=lr ----
        __syncthreads();   // all GEMM2 reads of previous hb complete (WAR)
#pragma unroll
        for (int mt = 0; mt < 4; ++mt)
#pragma unroll
            for (int nt = 0; nt < 2; ++nt)
#pragma unroll
                for (int r = 0; r < 4; ++r) {
                    int row = mt * 16 + lq * 4 + r;
                    int hl = hcol0 + nt * 16 + lr;
                    float v = acc1[mt][nt][r] + b1[hb * 256 + hl];
                    v = 0.5f * v * (1.0f + erff(v * 0.70710678118654752f));
                    int c = hl >> 3;
                    Hsm[row * 256 + ((c ^ (row & 7)) << 3) + (hl & 7)] = f2bb(v);
                }
        __syncthreads();
        // ---- GEMM2: acc2 += Hsm x W2 (register-direct B) over 256 h ----
#pragma unroll
        for (int kh = 0; kh < 8; ++kh) {
            short8 bf2[4];
#pragma unroll
            for (int nt = 0; nt < 4; ++nt)
                bf2[nt] = *(const short8*)&w2[(size_t)(ocol0 + nt * 16 + lr) * 2048 + hb * 256 + kh * 32 + lq * 8];
#pragma unroll
            for (int mt = 0; mt < 4; ++mt) {
                int row = mt * 16 + lr;
                int c = kh * 4 + lq;
                short8 ha = *(const short8*)&Hsm[row * 256 + ((c ^ (row & 7)) << 3)];
#pragma unroll
                for (int nt = 0; nt < 4; ++nt)
                    acc2[mt][nt] = __builtin_amdgcn_mfma_f32_16x16x32_bf16(ha, bf2[nt], acc2[mt][nt], 0, 0, 0);
            }
        }
    }
    // ---- epilogue: d_out[b][col][hw] = inp + acc2 + b2; hw contig per lane ----
    int b = mbase >> 10;
    int hwb = mbase & 1023;
#pragma unroll
    for (int mt = 0; mt < 4; ++mt) {
#pragma unroll
        for (int nt = 0; nt < 4; ++nt) {
            int col = ocol0 + nt * 16 + lr;
            size_t idx = ((size_t)(b * 512 + col)) * 1024 + hwb + mt * 16 + lq * 4;
            float4 xin = *(const float4*)&inp[idx];
            float4 o4;
            o4.x = xin.x + acc2[mt][nt][0] + b2v[nt];
            o4.y = xin.y + acc2[mt][nt][1] + b2v[nt];
            o4.z = xin.z + acc2[mt][nt][2] + b2v[nt];
            o4.w = xin.w + acc2[mt][nt][3] + b2v[nt];
            *(float4*)&outF[idx] = o4;
        }
    }
}

// ---------------------------------------------------------------------------
// K5: cosine attention per (b,h), MFMA. qkvp: Q,K [sect][bh][64 d][256 n];
// V transposed [bh][256 n][64 d]. Out attn_o [b*256+n][h*64+d] bf16.
// ---------------------------------------------------------------------------
__global__ __launch_bounds__(256) void attn_k(const ushort* __restrict__ qkvp,
                                              const float* __restrict__ mask_u,
                                              const float* __restrict__ temp,
                                              ushort* __restrict__ attn_out) {
    __shared__ float Sb[64 * 65];          // scores f32
    __shared__ ushort Pb[64 * 64];         // probs bf16, chunk^(row&7) swizzle
    __shared__ float fq[64], fk[64];
    int tid = threadIdx.x;
    int bh = blockIdx.x;
    int b = bh >> 3, h = bh & 7;
    const ushort* q  = qkvp + (size_t)bh * 16384;
    const ushort* k  = qkvp + 4194304 + (size_t)bh * 16384;
    const ushort* vt = qkvp + 8388608 + (size_t)bh * 16384;   // [256 n][64 d]
    int lane = tid & 63, w = tid >> 6;
    int lr = lane & 15, lq = lane >> 4;

    // ---- norms: 4 threads per row, 64 elems each ----
    {
        int row = tid >> 2, qd = tid & 3;
        const ushort* qr = q + row * 256 + qd * 64;
        const ushort* kr = k + row * 256 + qd * 64;
        float s = 0.f, t = 0.f;
#pragma unroll
        for (int i = 0; i < 8; ++i) {
            short8 a8 = *(const short8*)&qr[i * 8];
            short8 b8 = *(const short8*)&kr[i * 8];
#pragma unroll
            for (int j = 0; j < 8; ++j) {
                float fa = bf2f((ushort)a8[j]); s += fa * fa;
                float fb = bf2f((ushort)b8[j]); t += fb * fb;
            }
        }
        s += __shfl_xor(s, 1); s += __shfl_xor(s, 2);
        t += __shfl_xor(t, 1); t += __shfl_xor(t, 2);
        if (qd == 0) {
            fq[row] = 1.0f / fmaxf(sqrtf(s), 1e-12f);
            fk[row] = 1.0f / fmaxf(sqrtf(t), 1e-12f);
        }
    }
    __syncthreads();

    // ---- QK^T: 64x64, K=256. Wave quadrants 32x32 (2x2 tiles x 8 ksteps) ----
    int mq = (w >> 1) * 32, nq = (w & 1) * 32;
    f32x4 acc[2][2] = {};
    for (int kb = 0; kb < 256; kb += 32) {
        short8 af[2], bfr[2];
#pragma unroll
        for (int ti = 0; ti < 2; ++ti)
            af[ti] = *(const short8*)&q[(mq + ti * 16 + lr) * 256 + kb + lq * 8];
#pragma unroll
        for (int tj = 0; tj < 2; ++tj)
            bfr[tj] = *(const short8*)&k[(nq + tj * 16 + lr) * 256 + kb + lq * 8];
#pragma unroll
        for (int i = 0; i < 2; ++i)
#pragma unroll
            for (int j = 0; j < 2; ++j)
                acc[i][j] = __builtin_amdgcn_mfma_f32_16x16x32_bf16(af[i], bfr[j], acc[i][j], 0, 0, 0);
    }

    // ---- scale, mask, write S to LDS ----
    float tv = temp[h];
#pragma unroll
    for (int i = 0; i < 2; ++i)
#pragma unroll
        for (int r = 0; r < 4; ++r) {
            int d = mq + i * 16 + lq * 4 + r;
#pragma unroll
            for (int j = 0; j < 2; ++j) {
                int e = nq + j * 16 + lr;
                float sc = acc[i][j][r] * fq[d] * fk[e] * tv;
                float mu = mask_u[((size_t)bh * 64 + d) * 64 + e];
                if (mu < 0.2f) sc -= 1e12f;
                Sb[d * 65 + e] = sc;
            }
        }
    __syncthreads();

    // ---- softmax rows + pack P -> bf16 swizzled Pb ----
    {
        int row = tid >> 2, sub = tid & 3;
        float ev[16];
        float mx = -INFINITY;
#pragma unroll
        for (int i = 0; i < 16; ++i) { float s = Sb[row * 65 + sub * 16 + i]; ev[i] = s; mx = fmaxf(mx, s); }
        mx = fmaxf(mx, __shfl_xor(mx, 1));
        mx = fmaxf(mx, __shfl_xor(mx, 2));
        float sum = 0.f;
#pragma unroll
        for (int i = 0; i < 16; ++i) { ev[i] = expf(ev[i] - mx); sum += ev[i]; }
        sum += __shfl_xor(sum, 1);
        sum += __shfl_xor(sum, 2);
        float inv = 1.0f / sum;
        unsigned int* Pb32 = (unsigned int*)Pb;
#pragma unroll
        for (int kk = 0; kk < 8; ++kk) {
            unsigned int lo = f2bb(ev[2 * kk] * inv);
            unsigned int hi = f2bb(ev[2 * kk + 1] * inv);
            int c8 = sub * 2 + (kk >> 2);
            int ph = c8 ^ (row & 7);
            Pb32[row * 32 + ph * 4 + (kk & 3)] = (hi << 16) | lo;
        }
    }
    __syncthreads();

    // ---- PV: O[64 d][256 n] = P[64][64] * Vt[n][e]. Wave owns 64-n strip ----
    int nw = w * 64;
    f32x4 o[4][4] = {};
#pragma unroll
    for (int ks = 0; ks < 2; ++ks) {
        short8 pa[4];
#pragma unroll
        for (int mt = 0; mt < 4; ++mt) {
            int d = mt * 16 + lr;
            int ph = (ks * 4 + lq) ^ (d & 7);
            pa[mt] = *(const short8*)&Pb[d * 64 + ph * 8];
        }
#pragma unroll
        for (int nt = 0; nt < 4; ++nt) {
            short8 vb = *(const short8*)&vt[(size_t)(nw + nt * 16 + lr) * 64 + ks * 32 + lq * 8];
#pragma unroll
            for (int mt = 0; mt < 4; ++mt)
                o[mt][nt] = __builtin_amdgcn_mfma_f32_16x16x32_bf16(pa[mt], vb, o[mt][nt], 0, 0, 0);
        }
    }

    // ---- store O: attn_o[b*256+n][h*64+d], 8B packed per (mt,nt) ----
#pragma unroll
    for (int mt = 0; mt < 4; ++mt) {
        int d0 = mt * 16 + lq * 4;
#pragma unroll
        for (int nt = 0; nt < 4; ++nt) {
            int n = nw + nt * 16 + lr;
            ushort4v ov;
#pragma unroll
            for (int r = 0; r < 4; ++r) ov[r] = f2bb(o[mt][nt][r]);
            *(ushort4v*)&attn_out[((size_t)(b * 256 + n)) * 512 + h * 64 + d0] = ov;
        }
    }
}

// ---------------------------------------------------------------------------
extern "C" void kernel_launch(void* const* d_in, const int* in_sizes, int n_in,
                              void* d_out, int out_size, void* d_ws, size_t ws_size,
                              hipStream_t stream) {
    const float* x      = (const float*)d_in[0];
    const float* mask_u = (const float*)d_in[1];
    const float* dw_w   = (const float*)d_in[2];
    const float* dw_b   = (const float*)d_in[3];
    const float* ln1_g  = (const float*)d_in[4];
    const float* ln1_b  = (const float*)d_in[5];
    const float* qkv_w  = (const float*)d_in[6];
    const float* qkv_b  = (const float*)d_in[7];
    const float* temp   = (const float*)d_in[8];
    const float* proj_w = (const float*)d_in[9];
    const float* proj_b = (const float*)d_in[10];
    const float* ct_w   = (const float*)d_in[11];
    const float* ct_b   = (const float*)d_in[12];
    const float* ln2_g  = (const float*)d_in[13];
    const float* ln2_b  = (const float*)d_in[14];
    const float* pw1_w  = (const float*)d_in[15];
    const float* pw1_b  = (const float*)d_in[16];
    const float* pw2_w  = (const float*)d_in[17];
    const float* pw2_b  = (const float*)d_in[18];

    char* wsb = (char*)d_ws;
    float* mean1 = (float*)wsb;
    float* rstd1 = mean1 + 8192;
    ushort* wq = (ushort*)(wsb + 524288);
    ushort* wp = wq + 786432;
    ushort* wc = wp + 262144;
    ushort* w1 = wc + 1048576;
    ushort* w2 = w1 + 1048576;
    ushort* xp     = (ushort*)(wsb + 8912896);   // region A: 8 MiB
    ushort* t2     = xp;                         // A reuse
    ushort* a_ln   = (ushort*)(wsb + 17301504);  // region Br: 8 MiB
    ushort* yB     = a_ln;                       // Br reuse: y0 rows 0..8191
    ushort* qkvp   = (ushort*)(wsb + 25690112);  // region CD: 24 MiB
    ushort* attn_o = (ushort*)(wsb + 50855936);  // CD tail: 8 MiB
    ushort* yT     = (ushort*)(wsb + 59244544);  // region T: 24 MiB

    // 0. weight conversions
    cvtw_k<<<768,  256, 0, stream>>>(qkv_w,  wq, 196608);
    cvtw_k<<<256,  256, 0, stream>>>(proj_w, wp, 65536);
    cvtw_k<<<1024, 256, 0, stream>>>(pw1_w,  w1, 262144);
    cvtw_k<<<1024, 256, 0, stream>>>(pw2_w,  w2, 262144);
    cvtt_k<<<dim3(64, 16), 256, 0, stream>>>(ct_w, wc);
    // 1. depthwise conv + residual + avgpool
    dwpool_k<<<32 * 512, 256, 0, stream>>>(x, dw_w, dw_b, xp);
    // 2-3. LN1 stats + apply/transpose -> a_ln
    ln1_stats_k<<<128, 256, 0, stream>>>(xp, mean1, rstd1);
    ln1_apply_k<<<1024, 256, 0, stream>>>(xp, mean1, rstd1, ln1_g, ln1_b, a_ln);
    // 4. QKV gemm -> qkvp (Q/K permuted, V transposed)
    {
        GP p{}; p.A = a_ln; p.W = wq; p.bias = qkv_b; p.outB = qkvp; p.K = 512;
        mgemm_k<0, 128><<<dim3(12, 64), 256, 0, stream>>>(p);
    }
    // 5. attention (MFMA)
    attn_k<<<256, 256, 0, stream>>>(qkvp, mask_u, temp, attn_o);
    // 6. proj gemm (x2) -> t2
    {
        GP p{}; p.A = attn_o; p.W = wp; p.bias = proj_b; p.outB = t2; p.K = 512;
        mgemm_k<1, 128><<<dim3(4, 64), 256, 0, stream>>>(p);
    }
    // 7. convT gemm -> y0 (split yB/yT), channels-last
    {
        GP p{}; p.A = t2; p.W = wc; p.bias = ct_b;
        p.outB = yB; p.outB2 = yT; p.K = 512;
        mgemm_k<2, 128><<<dim3(16, 64), 256, 0, stream>>>(p);
    }
    // 8. LN2 fused stats+normalize in place
    ln2_fuse_k<<<8192, 256, 0, stream>>>(yB, yT, ln2_g, ln2_b);
    // 9. fused MLP: one dispatch, whole 32768 rows
    mlp_fused_k<<<512, 512, 0, stream>>>(yB, yT, w1, w2, pw1_b, pw2_b,
                                         x, (float*)d_out);
}